// Round 3
// baseline (854.045 us; speedup 1.0000x reference)
//
#include <hip/hip_runtime.h>
#include <stdint.h>

#define NP 2048
#define KNN 40
#define CAP 128          // candidate buffer per row (2 slots of 64, int — proven type)

__device__ __forceinline__ unsigned fOrd(float f) {
    unsigned u = __float_as_uint(f);
    return u ^ ((unsigned)((int)u >> 31) | 0x80000000u);
}
__device__ __forceinline__ unsigned long long dOrd(double d) {
    unsigned long long u = (unsigned long long)__double_as_longlong(d);
    return u ^ (((unsigned long long)((long long)u >> 63)) | 0x8000000000000000ull);
}

// 64-lane sum reduce of a packed counter (fields must not overflow 16/10 bits)
__device__ __forceinline__ unsigned wsum(unsigned pk) {
    pk += __shfl_xor((int)pk, 1);
    pk += __shfl_xor((int)pk, 2);
    pk += __shfl_xor((int)pk, 4);
    pk += __shfl_xor((int)pk, 8);
    pk += __shfl_xor((int)pk, 16);
    pk += __shfl_xor((int)pk, 32);
    return pk;
}

// ---------------------------------------------------------------------------
// prep: per point: xx = sum x^2 (fp32), p[o] = Wd[o,:]·x, r[o] = (Wc-Wd)[o,:]·x,
// XT[b][n][0..CP) = x (point-contiguous, zero-padded) + fp64 norm at offset CP
// (sequential c-order — must match refine's usage).
// ---------------------------------------------------------------------------
template<int C, int CP, int CPX>
__global__ void prep_kernel(const float* __restrict__ X, long bstride,
                            const float* __restrict__ W,
                            float* __restrict__ p, float* __restrict__ r,
                            float* __restrict__ xx, float* __restrict__ XT) {
    __shared__ float wdT[C][32];
    __shared__ float wrT[C][32];
    int tid = threadIdx.x;
    for (int i = tid; i < 32 * C; i += 256) {
        int o = i / C, c = i - o * C;
        float wd = W[o * 2 * C + c];
        float wc = W[o * 2 * C + C + c];
        wdT[c][o] = wd;
        wrT[c][o] = wc - wd;
    }
    __syncthreads();
    int lane = tid & 63;
    int o = lane & 31;
    int h = lane >> 5;
    int wv = tid >> 6;
    int flat = blockIdx.x * 8 + wv * 2 + h;   // 2048 wgs * 8 points = B*N
    int b = flat >> 11, n = flat & 2047;
    const float* Xb = X + (long)b * bstride + n;
    float pacc = 0.f, racc = 0.f, xxa = 0.f, xto = 0.f;
    double xxd = 0.0;
#pragma unroll
    for (int c = 0; c < C; c++) {
        float xv = Xb[(long)c * NP];
        pacc = fmaf(wdT[c][o], xv, pacc);
        racc = fmaf(wrT[c][o], xv, racc);
        xxa += xv * xv;
        xxd += (double)xv * (double)xv;       // sequential c order (refine-consistent)
        if (c == o) xto = xv;
    }
    long base = ((long)b * NP + n) * 32 + o;
    p[base] = pacc;
    r[base] = racc;
    long rowb = ((long)b * NP + n) * CPX;
    if (o < CP) XT[rowb + o] = (o < C) ? xto : 0.f;
    if (o == 0) {
        xx[b * NP + n] = xxa;
        *reinterpret_cast<double*>(&XT[rowb + CP]) = xxd;
    }
}

// ---------------------------------------------------------------------------
// knn: per (b,n) row. Proven design rules retained (R2-R18). Paired-row
// select phases (R17). R19 (this round): BALLOT-FREE selection — every
// __popcll(__ballot()) was v_cmp->SGPR + s_bcnt+s_add on the ONE scalar
// unit per CU (~4.4k SALU/wave, ~59us serialized per CU at 32 waves).
// Replaced by per-lane VALU counts (+= bool, split accumulators) + ONE
// packed shfl_xor tree per step (both rows share the tree; counts are
// bit-identical to the ballot version so vA/thr/V/tm and the selected
// SET are unchanged). Compaction positions now come from LDS atomicAdd
// (candidate order and sel order are provably irrelevant: refine
// re-ranks exactly by (key,idx); gather-reduce is order-insensitive;
// BN sums already use float atomics). DS ops of one wave execute in
// order, so counter reads after the emission atomics are safe.
// wg = 256 = 4 waves; each wave owns 2 rows; 2048 wgs (256 per batch).
// ---------------------------------------------------------------------------
template<int C, int CP, int CPX>
__global__ __launch_bounds__(256, 2)
void knn_kernel(const float* __restrict__ X, long bstride,
                const float* __restrict__ p, const float* __restrict__ r,
                const float* __restrict__ xx, const float* __restrict__ XT,
                float* __restrict__ mmax, float* __restrict__ mmin,
                float* __restrict__ sums) {
    __shared__ __align__(16) float xt[2][C * 128]; // two 128-tiles per round
    __shared__ __align__(16) float xxt[256];
    __shared__ __align__(8) float qld[4][CP][2];   // [wave][c][rowA/rowB]
    __shared__ int sel[8][KNN];
    __shared__ int cand[8][CAP];
    __shared__ int ccnt[8];                        // candidate counters
    __shared__ int scnt[8];                        // sel counters
    __shared__ float S1loc[32], S2loc[32];
    int tid = threadIdx.x;
    if (tid < 32) { S1loc[tid] = 0.f; S2loc[tid] = 0.f; }
    if (tid < 8) { ccnt[tid] = 0; scnt[tid] = 0; } // visible after first barrier
    for (int i = tid; i < 8 * KNN; i += 256) ((int*)sel)[i] = 0;   // defensive init
    int lane = tid & 63;
    int wv = tid >> 6;
    int half = lane >> 5;                 // which of the 2 staged tiles
    int l32 = lane & 31;
    int b = blockIdx.x >> 8;              // 256 wgs per batch
    int n0 = (blockIdx.x & 255) * 8;
    int nA = n0 + wv * 2, nB = nA + 1;
    int rowA = wv * 2, rowB = rowA + 1;
    const float* Xb = X + (long)b * bstride;
    const float* XTb = XT + (long)b * NP * CPX;
    long bNP = (long)b * NP;

    // queries -> LDS (wave-private rows; barrier below covers visibility)
    if (lane < CP) {
        qld[wv][lane][0] = XTb[(long)nA * CPX + lane];
        qld[wv][lane][1] = XTb[(long)nB * CPX + lane];
    }
    float xxnA = xx[bNP + nA];
    float xxnB = xx[bNP + nB];

    unsigned uA[16], uB[16];   // 16-bit keys packed 2/reg; slot 2*t2+s, s=j>>1
    for (int t2 = 0; t2 < 8; t2++) {
        __syncthreads();
        // stage tiles 2*t2 (->xt[0]) and 2*t2+1 (->xt[1]); R10 staging pattern
        for (int i = tid; i < C * 64; i += 256) {
            int c = i >> 6, g = i & 63;
            int tt = g >> 5, gg = g & 31;
            *(float4*)&xt[tt][c * 128 + gg * 4] =
                *(const float4*)&Xb[(long)c * NP + (t2 * 2 + tt) * 128 + gg * 4];
        }
        xxt[tid] = xx[bNP + t2 * 256 + tid];
        __syncthreads();
        const float* xth = xt[half];
        float4 ia = make_float4(0.f, 0.f, 0.f, 0.f);
        float4 ib = make_float4(0.f, 0.f, 0.f, 0.f);
#pragma unroll
        for (int c = 0; c < C; c++) {
            float2 q = *(const float2*)&qld[wv][c][0];      // b64 broadcast
            float4 xv = *(const float4*)&xth[c * 128 + 4 * l32]; // ONE b128/c
            ia.x = fmaf(q.x, xv.x, ia.x);
            ia.y = fmaf(q.x, xv.y, ia.y);
            ia.z = fmaf(q.x, xv.z, ia.z);
            ia.w = fmaf(q.x, xv.w, ia.w);
            ib.x = fmaf(q.y, xv.x, ib.x);
            ib.y = fmaf(q.y, xv.y, ib.y);
            ib.z = fmaf(q.y, xv.z, ib.z);
            ib.w = fmaf(q.y, xv.w, ib.w);
        }
        float4 xm = *(const float4*)&xxt[half * 128 + 4 * l32];
        unsigned a0 = fOrd((xxnA - 2.0f * ia.x) + xm.x) >> 16;   // ref rounding
        unsigned a1 = fOrd((xxnA - 2.0f * ia.y) + xm.y) >> 16;
        unsigned a2 = fOrd((xxnA - 2.0f * ia.z) + xm.z) >> 16;
        unsigned a3 = fOrd((xxnA - 2.0f * ia.w) + xm.w) >> 16;
        unsigned b0 = fOrd((xxnB - 2.0f * ib.x) + xm.x) >> 16;
        unsigned b1 = fOrd((xxnB - 2.0f * ib.y) + xm.y) >> 16;
        unsigned b2_ = fOrd((xxnB - 2.0f * ib.z) + xm.z) >> 16;
        unsigned b3 = fOrd((xxnB - 2.0f * ib.w) + xm.w) >> 16;
        uA[2 * t2]     = (a1 << 16) | a0;
        uA[2 * t2 + 1] = (a3 << 16) | a2;
        uB[2 * t2]     = (b1 << 16) | b0;
        uB[2 * t2 + 1] = (b3 << 16) | b2_;
    }

    // hoist f64 self-norms (independent global loads, hide under select)
    double xxdA = *reinterpret_cast<const double*>(&XTb[(long)nA * CPX + CP]);
    double xxdB = *reinterpret_cast<const double*>(&XTb[(long)nB * CPX + CP]);

    // --- pass 1 select, BOTH rows: 16-step bitwise rank-40, per-lane counts ---
    unsigned vA = 0u, vB = 0u;
    for (int bit = 15; bit >= 0; bit--) {
        unsigned tA = vA | ((1u << bit) - 1u);
        unsigned tB = vB | ((1u << bit) - 1u);
        int cA0 = 0, cA1 = 0, cB0 = 0, cB1 = 0;   // split accumulators (dep chains)
#pragma unroll
        for (int t = 0; t < 16; t += 2) {
            unsigned ar0 = uA[t], ar1 = uA[t + 1];
            unsigned br0 = uB[t], br1 = uB[t + 1];
            cA0 += ((ar0 & 0xFFFFu) <= tA); cA0 += ((ar0 >> 16) <= tA);
            cA1 += ((ar1 & 0xFFFFu) <= tA); cA1 += ((ar1 >> 16) <= tA);
            cB0 += ((br0 & 0xFFFFu) <= tB); cB0 += ((br0 >> 16) <= tB);
            cB1 += ((br1 & 0xFFFFu) <= tB); cB1 += ((br1 >> 16) <= tB);
        }
        unsigned pk = wsum((unsigned)(cA0 + cA1) | ((unsigned)(cB0 + cB1) << 16));
        if ((pk & 0xFFFFu) < KNN) vA |= (1u << bit);
        if ((pk >> 16) < KNN) vB |= (1u << bit);
    }
    unsigned thrA = (vA > 0xFFFEu) ? 0xFFFFu : vA + 1u;   // +1 bucket (proven)
    unsigned thrB = (vB > 0xFFFEu) ? 0xFFFFu : vB + 1u;

    // --- candidate lists, BOTH rows: atomic compaction (order irrelevant) ---
#pragma unroll
    for (int kk = 0; kk < 16; kk++) {
        unsigned a = uA[kk], bb = uB[kk];
        int idx = (kk >> 1) * 256 + half * 128 + 4 * l32 + (kk & 1) * 2;
        if ((a & 0xFFFFu) <= thrA) { int q = atomicAdd(&ccnt[rowA], 1); if (q < CAP) cand[rowA][q] = idx; }
        if ((a >> 16)     <= thrA) { int q = atomicAdd(&ccnt[rowA], 1); if (q < CAP) cand[rowA][q] = idx + 1; }
        if ((bb & 0xFFFFu) <= thrB) { int q = atomicAdd(&ccnt[rowB], 1); if (q < CAP) cand[rowB][q] = idx; }
        if ((bb >> 16)     <= thrB) { int q = atomicAdd(&ccnt[rowB], 1); if (q < CAP) cand[rowB][q] = idx + 1; }
    }
    int ra = 0, rb = 0;                       // read counts (DS in-order per wave)
    if (lane == 0) ra = atomicAdd(&ccnt[rowA], 0);
    if (lane == 1) rb = atomicAdd(&ccnt[rowB], 0);
    int cntA = __shfl(ra, 0); cntA = cntA < CAP ? cntA : CAP;
    int cntB = __shfl(rb, 1); cntB = cntB < CAP ? cntB : CAP;

    // --- refine candidates in float64, BOTH rows (exact order preserved) ---
    unsigned long long keyA[CAP / 64], keyB[CAP / 64];
    int mixA[CAP / 64], mixB[CAP / 64];
#pragma unroll
    for (int s3 = 0; s3 < CAP / 64; s3++) {
        int slot = s3 * 64 + lane;
        keyA[s3] = ~0ull; mixA[s3] = 0;
        keyB[s3] = ~0ull; mixB[s3] = 0;
        if (slot < cntA) {
            int m = cand[rowA][slot] & (NP - 1);   // defensive mask
            mixA[s3] = m;
            const float* xmp = XTb + (long)m * CPX;
            double inner = 0.0;
#pragma unroll
            for (int g = 0; g < CP / 4; g++) {
                float4 v = *(const float4*)&xmp[g * 4];
                inner += (double)qld[wv][g * 4 + 0][0] * (double)v.x;
                inner += (double)qld[wv][g * 4 + 1][0] * (double)v.y;
                inner += (double)qld[wv][g * 4 + 2][0] * (double)v.z;
                inner += (double)qld[wv][g * 4 + 3][0] * (double)v.w;
            }
            double xxm = *reinterpret_cast<const double*>(&xmp[CP]);
            double dd = (xxdA - 2.0 * inner) + xxm;
            keyA[s3] = dOrd(dd);
        }
        if (slot < cntB) {
            int m = cand[rowB][slot] & (NP - 1);   // defensive mask
            mixB[s3] = m;
            const float* xmp = XTb + (long)m * CPX;
            double inner = 0.0;
#pragma unroll
            for (int g = 0; g < CP / 4; g++) {
                float4 v = *(const float4*)&xmp[g * 4];
                inner += (double)qld[wv][g * 4 + 0][1] * (double)v.x;
                inner += (double)qld[wv][g * 4 + 1][1] * (double)v.y;
                inner += (double)qld[wv][g * 4 + 2][1] * (double)v.z;
                inner += (double)qld[wv][g * 4 + 3][1] * (double)v.w;
            }
            double xxm = *reinterpret_cast<const double*>(&xmp[CP]);
            double dd = (xxdB - 2.0 * inner) + xxm;
            keyB[s3] = dOrd(dd);
        }
    }

    // --- rank-40 key, BOTH rows: 2-bit radix, per-lane counts + packed tree ---
    unsigned long long VA = 0ull, VB = 0ull;
    for (int bit = 62; bit >= 0; bit -= 2) {
        unsigned long long low = (1ull << bit) - 1ull;
        unsigned long long tA0 = VA | low;
        unsigned long long tA1 = VA | (1ull << bit) | low;
        unsigned long long tA2 = VA | (2ull << bit) | low;
        unsigned long long tB0 = VB | low;
        unsigned long long tB1 = VB | (1ull << bit) | low;
        unsigned long long tB2 = VB | (2ull << bit) | low;
        unsigned pA = 0, pB = 0;      // 3 counts in 10-bit fields (max 128 each)
#pragma unroll
        for (int s3 = 0; s3 < CAP / 64; s3++) {
            pA += (unsigned)(keyA[s3] <= tA0);
            pA += (unsigned)(keyA[s3] <= tA1) << 10;
            pA += (unsigned)(keyA[s3] <= tA2) << 20;
            pB += (unsigned)(keyB[s3] <= tB0);
            pB += (unsigned)(keyB[s3] <= tB1) << 10;
            pB += (unsigned)(keyB[s3] <= tB2) << 20;
        }
        pA = wsum(pA); pB = wsum(pB);
        int cA0 = pA & 1023, cA1 = (pA >> 10) & 1023, cA2 = pA >> 20;
        int cB0 = pB & 1023, cB1 = (pB >> 10) & 1023, cB2 = pB >> 20;
        if (cA0 >= KNN) { /* digit 0 */ }
        else if (cA1 >= KNN) VA |= (1ull << bit);
        else if (cA2 >= KNN) VA |= (2ull << bit);
        else VA |= (3ull << bit);
        if (cB0 >= KNN) { /* digit 0 */ }
        else if (cB1 >= KNN) VB |= (1ull << bit);
        else if (cB2 >= KNN) VB |= (2ull << bit);
        else VB |= (3ull << bit);
    }

    // --- strict-less counts (needed for tie quota), per-lane + tree ---
    {
        unsigned ps = 0;
#pragma unroll
        for (int s3 = 0; s3 < CAP / 64; s3++) {
            ps += (unsigned)(keyA[s3] < VA);
            ps += (unsigned)(keyB[s3] < VB) << 16;
        }
        ps = wsum(ps);
        int needA = KNN - (int)(ps & 0xFFFFu);
        int needB = KNN - (int)(ps >> 16);
        // --- tie threshold: lowest-index-first, 11-step bitwise select ---
        int tmA = 0, tmB = 0;
        for (int bit = 10; bit >= 0; bit--) {
            int tA = tmA | ((1 << bit) - 1);
            int tB = tmB | ((1 << bit) - 1);
            unsigned pk = 0;
#pragma unroll
            for (int s3 = 0; s3 < CAP / 64; s3++) {
                pk += (unsigned)(keyA[s3] == VA && mixA[s3] <= tA);
                pk += (unsigned)(keyB[s3] == VB && mixB[s3] <= tB) << 16;
            }
            pk = wsum(pk);
            if ((int)(pk & 0xFFFFu) < needA) tmA |= (1 << bit);
            if ((int)(pk >> 16) < needB) tmB |= (1 << bit);
        }
        // --- single emission pass: {k < V} ∪ {k == V && idx <= tm} ---
#pragma unroll
        for (int s3 = 0; s3 < CAP / 64; s3++) {
            bool pAo = (keyA[s3] < VA) || (keyA[s3] == VA && mixA[s3] <= tmA);
            bool pBo = (keyB[s3] < VB) || (keyB[s3] == VB && mixB[s3] <= tmB);
            if (pAo) { int q = atomicAdd(&scnt[rowA], 1); if (q < KNN) sel[rowA][q] = mixA[s3]; }
            if (pBo) { int q = atomicAdd(&scnt[rowB], 1); if (q < KNN) sel[rowB][q] = mixB[s3]; }
        }
    }

    // --- fused gather-reduce over the selected 40, BOTH rows ---
    {
        int o = lane & 31, h = lane >> 5;
        float s1A = 0.f, s2A = 0.f, s1B = 0.f, s2B = 0.f;
        float mxA = -__builtin_inff(), mnA = __builtin_inff();
        float mxB = -__builtin_inff(), mnB = __builtin_inff();
        const float* pb = p + bNP * 32 + o;
        for (int k = h * 20; k < h * 20 + 20; k++) {
            int mA = sel[rowA][k] & (NP - 1);          // defensive mask
            int mB = sel[rowB][k] & (NP - 1);
            float pvA = pb[(long)mA * 32];
            float pvB = pb[(long)mB * 32];
            s1A += pvA;
            s2A = fmaf(pvA, pvA, s2A);
            mxA = fmaxf(mxA, pvA);
            mnA = fminf(mnA, pvA);
            s1B += pvB;
            s2B = fmaf(pvB, pvB, s2B);
            mxB = fmaxf(mxB, pvB);
            mnB = fminf(mnB, pvB);
        }
        s1A += __shfl_xor(s1A, 32);
        s2A += __shfl_xor(s2A, 32);
        mxA = fmaxf(mxA, __shfl_xor(mxA, 32));
        mnA = fminf(mnA, __shfl_xor(mnA, 32));
        s1B += __shfl_xor(s1B, 32);
        s2B += __shfl_xor(s2B, 32);
        mxB = fmaxf(mxB, __shfl_xor(mxB, 32));
        mnB = fminf(mnB, __shfl_xor(mnB, 32));
        if (h == 0) {
            long bseA = (bNP + nA) * 32 + o;
            float qA = r[bseA];
            mmax[bseA] = mxA + qA;
            mmin[bseA] = mnA + qA;
            atomicAdd(&S1loc[o], s1A + 40.f * qA);
            atomicAdd(&S2loc[o], fmaf(2.f * qA, s1A, fmaf(40.f * qA, qA, s2A)));
            long bseB = (bNP + nB) * 32 + o;
            float qB = r[bseB];
            mmax[bseB] = mxB + qB;
            mmin[bseB] = mnB + qB;
            atomicAdd(&S1loc[o], s1B + 40.f * qB);
            atomicAdd(&S2loc[o], fmaf(2.f * qB, s1B, fmaf(40.f * qB, qB, s2B)));
        }
    }
    __syncthreads();
    if (tid < 32) {
        atomicAdd(&sums[tid], S1loc[tid]);
        atomicAdd(&sums[32 + tid], S2loc[tid]);
    }
}

// ---------------------------------------------------------------------------
// finish: per-channel BN affine from global sums, monotone max/min trick,
// LeakyReLU, residual, write slice of cat into d_out [B][128][N]
// ---------------------------------------------------------------------------
__global__ void finish_kernel(const float* __restrict__ mmax, const float* __restrict__ mmin,
                              const float* __restrict__ sums,
                              const float* __restrict__ g, const float* __restrict__ be,
                              const float* __restrict__ resid,
                              float* __restrict__ outb) {
    int id = blockIdx.x * 256 + threadIdx.x;     // B*32*N = 524288
    int b = id >> 16;
    int o = (id >> 11) & 31;
    int n = id & 2047;
    const float cntf = 655360.0f;                 // B*N*K
    float mean = sums[o] / cntf;
    float var = sums[32 + o] / cntf - mean * mean;
    float sc = g[o] / sqrtf(var + 1e-5f);
    float sh = be[o] - mean * sc;
    long bse = ((long)b * NP + n) * 32 + o;
    float v = (sc >= 0.f) ? mmax[bse] : mmin[bse];
    float y = sc * v + sh;
    y = (y >= 0.f) ? y : 0.2f * y;
    long ob = ((long)b * 128 + o) * NP + n;
    if (resid) y += resid[ob];
    outb[ob] = y;
}

// ---------------------------------------------------------------------------
// final in-place GEMM on d_out: out[b,o,n] = sum_c W5[o,c]*cat[b,c,n]
// ---------------------------------------------------------------------------
__global__ void final_gemm(const float* __restrict__ W5, float* __restrict__ out) {
    __shared__ __align__(16) float catL[128][32];
    int b = blockIdx.x >> 6;
    int n0 = (blockIdx.x & 63) * 32;
    int tid = threadIdx.x;
    for (int i = tid; i < 128 * 32; i += 256) {
        int c = i >> 5, nn = i & 31;
        catL[c][nn] = out[((long)b * 128 + c) * NP + n0 + nn];
    }
    __syncthreads();
    int og = tid >> 3, ng = tid & 7;
    int o0 = og * 4, nl = ng * 4;
    float acc[4][4] = {};
    for (int c = 0; c < 128; c++) {
        float4 cv = *(const float4*)&catL[c][nl];
#pragma unroll
        for (int i = 0; i < 4; i++) {
            float w = W5[(o0 + i) * 128 + c];
            acc[i][0] = fmaf(w, cv.x, acc[i][0]);
            acc[i][1] = fmaf(w, cv.y, acc[i][1]);
            acc[i][2] = fmaf(w, cv.z, acc[i][2]);
            acc[i][3] = fmaf(w, cv.w, acc[i][3]);
        }
    }
#pragma unroll
    for (int i = 0; i < 4; i++) {
        float4 vv = make_float4(acc[i][0], acc[i][1], acc[i][2], acc[i][3]);
        *(float4*)&out[((long)b * 128 + o0 + i) * NP + n0 + nl] = vv;
    }
}

extern "C" void kernel_launch(void* const* d_in, const int* in_sizes, int n_in,
                              void* d_out, int out_size, void* d_ws, size_t ws_size,
                              hipStream_t stream) {
    const float* x  = (const float*)d_in[0];
    const float* W1 = (const float*)d_in[1];
    const float* W2 = (const float*)d_in[2];
    const float* W3 = (const float*)d_in[3];
    const float* W4 = (const float*)d_in[4];
    const float* W5 = (const float*)d_in[5];
    const float* g1 = (const float*)d_in[6];
    const float* b1 = (const float*)d_in[7];
    const float* g2 = (const float*)d_in[8];
    const float* b2 = (const float*)d_in[9];
    const float* g3 = (const float*)d_in[10];
    const float* b3 = (const float*)d_in[11];
    const float* g4 = (const float*)d_in[12];
    const float* b4 = (const float*)d_in[13];
    float* out = (float*)d_out;
    float* ws  = (float*)d_ws;
    // ws layout (floats): p | r | mmax | mmin | xx | sums | XT
    float* p    = ws;
    float* r    = ws + 524288;
    float* mmax = ws + 1048576;
    float* mmin = ws + 1572864;
    float* xx   = ws + 2097152;
    float* sums = ws + 2113536;
    float* XT   = ws + 2113792;   // up to 8*2048*36 = 589824 floats
    hipMemsetAsync(sums, 0, 256 * sizeof(float), stream);

    // block 1 (C=9, CP=12, CPX=16)
    prep_kernel<9, 12, 16><<<2048, 256, 0, stream>>>(x, 9L * NP, W1, p, r, xx, XT);
    knn_kernel<9, 12, 16><<<2048, 256, 0, stream>>>(x, 9L * NP, p, r, xx, XT, mmax, mmin, sums);
    finish_kernel<<<2048, 256, 0, stream>>>(mmax, mmin, sums, g1, b1, nullptr, out);
    // block 2 (C=32, CP=32, CPX=36)
    const float* x1 = out;
    prep_kernel<32, 32, 36><<<2048, 256, 0, stream>>>(x1, 128L * NP, W2, p, r, xx, XT);
    knn_kernel<32, 32, 36><<<2048, 256, 0, stream>>>(x1, 128L * NP, p, r, xx, XT, mmax, mmin, sums + 64);
    finish_kernel<<<2048, 256, 0, stream>>>(mmax, mmin, sums + 64, g2, b2, x1, out + 32 * NP);
    // block 3
    const float* x2 = out + 32 * NP;
    prep_kernel<32, 32, 36><<<2048, 256, 0, stream>>>(x2, 128L * NP, W3, p, r, xx, XT);
    knn_kernel<32, 32, 36><<<2048, 256, 0, stream>>>(x2, 128L * NP, p, r, xx, XT, mmax, mmin, sums + 128);
    finish_kernel<<<2048, 256, 0, stream>>>(mmax, mmin, sums + 128, g3, b3, x2, out + 64 * NP);
    // block 4
    const float* x3 = out + 64 * NP;
    prep_kernel<32, 32, 36><<<2048, 256, 0, stream>>>(x3, 128L * NP, W4, p, r, xx, XT);
    knn_kernel<32, 32, 36><<<2048, 256, 0, stream>>>(x3, 128L * NP, p, r, xx, XT, mmax, mmin, sums + 192);
    finish_kernel<<<2048, 256, 0, stream>>>(mmax, mmin, sums + 192, g4, b4, x3, out + 96 * NP);

    final_gemm<<<512, 256, 0, stream>>>(W5, out);
}

// Round 4
// 682.953 us; speedup vs baseline: 1.2505x; 1.2505x over previous
//
#include <hip/hip_runtime.h>
#include <stdint.h>

#define NP 2048
#define KNN 40
#define CAP 128          // candidate buffer per row (2 slots of 64, int — proven type)

__device__ __forceinline__ unsigned fOrd(float f) {
    unsigned u = __float_as_uint(f);
    return u ^ ((unsigned)((int)u >> 31) | 0x80000000u);
}
__device__ __forceinline__ unsigned long long dOrd(double d) {
    unsigned long long u = (unsigned long long)__double_as_longlong(d);
    return u ^ (((unsigned long long)((long long)u >> 63)) | 0x8000000000000000ull);
}

// ---------------------------------------------------------------------------
// prep: per point: xx = sum x^2 (fp32), p[o] = Wd[o,:]·x, r[o] = (Wc-Wd)[o,:]·x,
// XT[b][n][0..CP) = x (point-contiguous, zero-padded) + fp64 norm at offset CP
// (sequential c-order — must match refine's usage).
// ---------------------------------------------------------------------------
template<int C, int CP, int CPX>
__global__ void prep_kernel(const float* __restrict__ X, long bstride,
                            const float* __restrict__ W,
                            float* __restrict__ p, float* __restrict__ r,
                            float* __restrict__ xx, float* __restrict__ XT) {
    __shared__ float wdT[C][32];
    __shared__ float wrT[C][32];
    int tid = threadIdx.x;
    for (int i = tid; i < 32 * C; i += 256) {
        int o = i / C, c = i - o * C;
        float wd = W[o * 2 * C + c];
        float wc = W[o * 2 * C + C + c];
        wdT[c][o] = wd;
        wrT[c][o] = wc - wd;
    }
    __syncthreads();
    int lane = tid & 63;
    int o = lane & 31;
    int h = lane >> 5;
    int wv = tid >> 6;
    int flat = blockIdx.x * 8 + wv * 2 + h;   // 2048 wgs * 8 points = B*N
    int b = flat >> 11, n = flat & 2047;
    const float* Xb = X + (long)b * bstride + n;
    float pacc = 0.f, racc = 0.f, xxa = 0.f, xto = 0.f;
    double xxd = 0.0;
#pragma unroll
    for (int c = 0; c < C; c++) {
        float xv = Xb[(long)c * NP];
        pacc = fmaf(wdT[c][o], xv, pacc);
        racc = fmaf(wrT[c][o], xv, racc);
        xxa += xv * xv;
        xxd += (double)xv * (double)xv;       // sequential c order (refine-consistent)
        if (c == o) xto = xv;
    }
    long base = ((long)b * NP + n) * 32 + o;
    p[base] = pacc;
    r[base] = racc;
    long rowb = ((long)b * NP + n) * CPX;
    if (o < CP) XT[rowb + o] = (o < C) ? xto : 0.f;
    if (o == 0) {
        xx[b * NP + n] = xxa;
        *reinterpret_cast<double*>(&XT[rowb + CP]) = xxd;
    }
}

// ---------------------------------------------------------------------------
// knn: per (b,n) row. Proven rules R2-R18 retained. R17: paired-row select.
// R19 RETIRED (ballot-free + LDS-atomic compaction regressed: moved SALU
// work onto the busier VALU pipe, atomics serialized 64-way; 165->203us).
// R20 (this round): post-refine rank select (was radix64 32 steps + strict
// + tie-bisect 11 steps + ballot emission ~ 45 serial ballot rounds) is
// replaced by ONE in-register bitonic sort of the <=128 candidates by
// (f64 key, idx) using constant-mask shfl_xor (DPP/swizzle, zero SALU,
// zero LDS) + direct rank emission (lane j<40 writes sel[row][j]).
// Selecting the 40 lexicographically-smallest (key,idx) pairs is provably
// the same set as {k<V} u {k==V && idx<=tm} — numerics & ties unchanged.
// Fast path: 64-elem sort (21 stages) when both rows have <=64 candidates;
// else full 128-elem 2-slot sort (28 stages). Pass-1 ballot bisect and
// ballot-prefix compaction are byte-identical to the proven R2 kernel.
// wg = 256 = 4 waves; each wave owns 2 rows; 2048 wgs (256 per batch).
// ---------------------------------------------------------------------------
template<int C, int CP, int CPX>
__global__ __launch_bounds__(256, 2)
void knn_kernel(const float* __restrict__ X, long bstride,
                const float* __restrict__ p, const float* __restrict__ r,
                const float* __restrict__ xx, const float* __restrict__ XT,
                float* __restrict__ mmax, float* __restrict__ mmin,
                float* __restrict__ sums) {
    __shared__ __align__(16) float xt[2][C * 128]; // two 128-tiles per round
    __shared__ __align__(16) float xxt[256];
    __shared__ __align__(8) float qld[4][CP][2];   // [wave][c][rowA/rowB]
    __shared__ int sel[8][KNN];
    __shared__ int cand[8][CAP];
    __shared__ float S1loc[32], S2loc[32];
    int tid = threadIdx.x;
    if (tid < 32) { S1loc[tid] = 0.f; S2loc[tid] = 0.f; }
    for (int i = tid; i < 8 * KNN; i += 256) ((int*)sel)[i] = 0;   // defensive init
    int lane = tid & 63;
    int wv = tid >> 6;
    int half = lane >> 5;                 // which of the 2 staged tiles
    int l32 = lane & 31;
    int b = blockIdx.x >> 8;              // 256 wgs per batch
    int n0 = (blockIdx.x & 255) * 8;
    int nA = n0 + wv * 2, nB = nA + 1;
    int rowA = wv * 2, rowB = rowA + 1;
    const float* Xb = X + (long)b * bstride;
    const float* XTb = XT + (long)b * NP * CPX;
    long bNP = (long)b * NP;

    // queries -> LDS (wave-private rows; barrier below covers visibility)
    if (lane < CP) {
        qld[wv][lane][0] = XTb[(long)nA * CPX + lane];
        qld[wv][lane][1] = XTb[(long)nB * CPX + lane];
    }
    float xxnA = xx[bNP + nA];
    float xxnB = xx[bNP + nB];

    unsigned uA[16], uB[16];   // 16-bit keys packed 2/reg; slot 2*t2+s, s=j>>1
    for (int t2 = 0; t2 < 8; t2++) {
        __syncthreads();
        // stage tiles 2*t2 (->xt[0]) and 2*t2+1 (->xt[1]); R10 staging pattern
        for (int i = tid; i < C * 64; i += 256) {
            int c = i >> 6, g = i & 63;
            int tt = g >> 5, gg = g & 31;
            *(float4*)&xt[tt][c * 128 + gg * 4] =
                *(const float4*)&Xb[(long)c * NP + (t2 * 2 + tt) * 128 + gg * 4];
        }
        xxt[tid] = xx[bNP + t2 * 256 + tid];
        __syncthreads();
        const float* xth = xt[half];
        float4 ia = make_float4(0.f, 0.f, 0.f, 0.f);
        float4 ib = make_float4(0.f, 0.f, 0.f, 0.f);
#pragma unroll
        for (int c = 0; c < C; c++) {
            float2 q = *(const float2*)&qld[wv][c][0];      // b64 broadcast
            float4 xv = *(const float4*)&xth[c * 128 + 4 * l32]; // ONE b128/c
            ia.x = fmaf(q.x, xv.x, ia.x);
            ia.y = fmaf(q.x, xv.y, ia.y);
            ia.z = fmaf(q.x, xv.z, ia.z);
            ia.w = fmaf(q.x, xv.w, ia.w);
            ib.x = fmaf(q.y, xv.x, ib.x);
            ib.y = fmaf(q.y, xv.y, ib.y);
            ib.z = fmaf(q.y, xv.z, ib.z);
            ib.w = fmaf(q.y, xv.w, ib.w);
        }
        float4 xm = *(const float4*)&xxt[half * 128 + 4 * l32];
        unsigned a0 = fOrd((xxnA - 2.0f * ia.x) + xm.x) >> 16;   // ref rounding
        unsigned a1 = fOrd((xxnA - 2.0f * ia.y) + xm.y) >> 16;
        unsigned a2 = fOrd((xxnA - 2.0f * ia.z) + xm.z) >> 16;
        unsigned a3 = fOrd((xxnA - 2.0f * ia.w) + xm.w) >> 16;
        unsigned b0 = fOrd((xxnB - 2.0f * ib.x) + xm.x) >> 16;
        unsigned b1 = fOrd((xxnB - 2.0f * ib.y) + xm.y) >> 16;
        unsigned b2_ = fOrd((xxnB - 2.0f * ib.z) + xm.z) >> 16;
        unsigned b3 = fOrd((xxnB - 2.0f * ib.w) + xm.w) >> 16;
        uA[2 * t2]     = (a1 << 16) | a0;
        uA[2 * t2 + 1] = (a3 << 16) | a2;
        uB[2 * t2]     = (b1 << 16) | b0;
        uB[2 * t2 + 1] = (b3 << 16) | b2_;
    }

    unsigned long long lmlt = (1ull << lane) - 1ull;

    // hoist f64 self-norms (independent global loads, hide under select)
    double xxdA = *reinterpret_cast<const double*>(&XTb[(long)nA * CPX + CP]);
    double xxdB = *reinterpret_cast<const double*>(&XTb[(long)nB * CPX + CP]);

    // --- pass 1 select, BOTH rows: fixed 16-step bitwise rank-40 select ---
    unsigned vA = 0u, vB = 0u;
    for (int bit = 15; bit >= 0; bit--) {
        unsigned tA = vA | ((1u << bit) - 1u);
        unsigned tB = vB | ((1u << bit) - 1u);
        int cA = 0, cB = 0;
#pragma unroll
        for (int t = 0; t < 16; t++) {
            cA += __popcll(__ballot((uA[t] & 0xFFFFu) <= tA));
            cA += __popcll(__ballot((uA[t] >> 16) <= tA));
            cB += __popcll(__ballot((uB[t] & 0xFFFFu) <= tB));
            cB += __popcll(__ballot((uB[t] >> 16) <= tB));
        }
        if (cA < KNN) vA |= (1u << bit);
        if (cB < KNN) vB |= (1u << bit);
    }
    unsigned thrA = (vA > 0xFFFEu) ? 0xFFFFu : vA + 1u;   // +1 bucket (proven)
    unsigned thrB = (vB > 0xFFFEu) ? 0xFFFFu : vB + 1u;

    // --- candidate lists, BOTH rows (m = t2*256 + half*128 + 4*l32 + j) ---
    int baseA = 0, baseB = 0;
#pragma unroll
    for (int kk = 0; kk < 16; kk++) {
#pragma unroll
        for (int hh = 0; hh < 2; hh++) {
            unsigned kA = hh ? (uA[kk] >> 16) : (uA[kk] & 0xFFFFu);
            unsigned kB = hh ? (uB[kk] >> 16) : (uB[kk] & 0xFFFFu);
            int idx = (kk >> 1) * 256 + half * 128 + 4 * l32 + (kk & 1) * 2 + hh;
            bool pA = (kA <= thrA), pB = (kB <= thrB);
            unsigned long long mkA = __ballot(pA), mkB = __ballot(pB);
            if (pA) {
                int pos = baseA + __popcll(mkA & lmlt);
                if (pos < CAP) cand[rowA][pos] = idx;
            }
            if (pB) {
                int pos = baseB + __popcll(mkB & lmlt);
                if (pos < CAP) cand[rowB][pos] = idx;
            }
            baseA += __popcll(mkA);
            baseB += __popcll(mkB);
        }
    }
    int cntA = baseA < CAP ? baseA : CAP;
    int cntB = baseB < CAP ? baseB : CAP;

    // --- refine candidates in float64, BOTH rows (exact order preserved) ---
    unsigned long long keyA[CAP / 64], keyB[CAP / 64];
    int mixA[CAP / 64], mixB[CAP / 64];
#pragma unroll
    for (int s3 = 0; s3 < CAP / 64; s3++) {
        int slot = s3 * 64 + lane;
        keyA[s3] = ~0ull; mixA[s3] = 0;
        keyB[s3] = ~0ull; mixB[s3] = 0;
        if (slot < cntA) {
            int m = cand[rowA][slot] & (NP - 1);   // defensive mask
            mixA[s3] = m;
            const float* xmp = XTb + (long)m * CPX;
            double inner = 0.0;
#pragma unroll
            for (int g = 0; g < CP / 4; g++) {
                float4 v = *(const float4*)&xmp[g * 4];
                inner += (double)qld[wv][g * 4 + 0][0] * (double)v.x;
                inner += (double)qld[wv][g * 4 + 1][0] * (double)v.y;
                inner += (double)qld[wv][g * 4 + 2][0] * (double)v.z;
                inner += (double)qld[wv][g * 4 + 3][0] * (double)v.w;
            }
            double xxm = *reinterpret_cast<const double*>(&xmp[CP]);
            double dd = (xxdA - 2.0 * inner) + xxm;
            keyA[s3] = dOrd(dd);
        }
        if (slot < cntB) {
            int m = cand[rowB][slot] & (NP - 1);   // defensive mask
            mixB[s3] = m;
            const float* xmp = XTb + (long)m * CPX;
            double inner = 0.0;
#pragma unroll
            for (int g = 0; g < CP / 4; g++) {
                float4 v = *(const float4*)&xmp[g * 4];
                inner += (double)qld[wv][g * 4 + 0][1] * (double)v.x;
                inner += (double)qld[wv][g * 4 + 1][1] * (double)v.y;
                inner += (double)qld[wv][g * 4 + 2][1] * (double)v.z;
                inner += (double)qld[wv][g * 4 + 3][1] * (double)v.w;
            }
            double xxm = *reinterpret_cast<const double*>(&xmp[CP]);
            double dd = (xxdB - 2.0 * inner) + xxm;
            keyB[s3] = dOrd(dd);
        }
    }

    // --- R20: rank select via in-register bitonic sort by (key, idx) ---
    // compare-exchange with partner lane^S; keepmin decides which end we keep
    auto cex = [](unsigned long long& k, int& i, const int S, const bool keepmin) {
        unsigned long long pk = __shfl_xor(k, S);
        int pi = __shfl_xor(i, S);
        bool less = (k < pk) || (k == pk && i < pi);
        bool tp = (less != keepmin);
        k = tp ? pk : k;
        i = tp ? pi : i;
    };
    if (cntA <= 64 && cntB <= 64) {
        // 64-element ascending bitonic sort, slot0 only (21 stages)
#pragma unroll
        for (int kk2 = 1; kk2 <= 6; kk2++) {
            const int K = 1 << kk2;
#pragma unroll
            for (int ss = kk2 - 1; ss >= 0; ss--) {
                const int S = 1 << ss;
                bool asc0 = (K == 64) ? true : ((lane & K) == 0);
                bool km0 = ((lane & S) == 0) == asc0;
                cex(keyA[0], mixA[0], S, km0);
                cex(keyB[0], mixB[0], S, km0);
            }
        }
    } else {
        // 128-element ascending bitonic sort, 2 slots/lane (element j = s3*64+lane)
#pragma unroll
        for (int kk2 = 1; kk2 <= 6; kk2++) {
            const int K = 1 << kk2;
#pragma unroll
            for (int ss = kk2 - 1; ss >= 0; ss--) {
                const int S = 1 << ss;
                bool ascL = (lane & K) == 0;
                bool asc0 = (K == 64) ? true  : ascL;   // j&64 = 0 for slot0
                bool asc1 = (K == 64) ? false : ascL;   // j&64 = 64 for slot1
                bool km0 = ((lane & S) == 0) == asc0;
                bool km1 = ((lane & S) == 0) == asc1;
                cex(keyA[0], mixA[0], S, km0);
                cex(keyA[1], mixA[1], S, km1);
                cex(keyB[0], mixB[0], S, km0);
                cex(keyB[1], mixB[1], S, km1);
            }
        }
        // K=128 level. s=64: local exchange between slots (ascending: e0=min)
        {
            bool lA = (keyA[0] < keyA[1]) || (keyA[0] == keyA[1] && mixA[0] < mixA[1]);
            unsigned long long tk = keyA[0]; int ti = mixA[0];
            keyA[0] = lA ? keyA[0] : keyA[1];  mixA[0] = lA ? mixA[0] : mixA[1];
            keyA[1] = lA ? keyA[1] : tk;       mixA[1] = lA ? mixA[1] : ti;
            bool lB = (keyB[0] < keyB[1]) || (keyB[0] == keyB[1] && mixB[0] < mixB[1]);
            tk = keyB[0]; ti = mixB[0];
            keyB[0] = lB ? keyB[0] : keyB[1];  mixB[0] = lB ? mixB[0] : mixB[1];
            keyB[1] = lB ? keyB[1] : tk;       mixB[1] = lB ? mixB[1] : ti;
        }
        // s = 32..1, ascending everywhere (j&128 == 0)
#pragma unroll
        for (int ss = 5; ss >= 0; ss--) {
            const int S = 1 << ss;
            bool km = ((lane & S) == 0);
            cex(keyA[0], mixA[0], S, km);
            cex(keyA[1], mixA[1], S, km);
            cex(keyB[0], mixB[0], S, km);
            cex(keyB[1], mixB[1], S, km);
        }
    }
    // ranks 0..63 now live in slot0 by lane; emit the 40 smallest (key,idx)
    if (lane < KNN) {
        sel[rowA][lane] = mixA[0];
        sel[rowB][lane] = mixB[0];
    }

    // --- fused gather-reduce over the selected 40, BOTH rows ---
    {
        int o = lane & 31, h = lane >> 5;
        float s1A = 0.f, s2A = 0.f, s1B = 0.f, s2B = 0.f;
        float mxA = -__builtin_inff(), mnA = __builtin_inff();
        float mxB = -__builtin_inff(), mnB = __builtin_inff();
        const float* pb = p + bNP * 32 + o;
        for (int k = h * 20; k < h * 20 + 20; k++) {
            int mA = sel[rowA][k] & (NP - 1);          // defensive mask
            int mB = sel[rowB][k] & (NP - 1);
            float pvA = pb[(long)mA * 32];
            float pvB = pb[(long)mB * 32];
            s1A += pvA;
            s2A = fmaf(pvA, pvA, s2A);
            mxA = fmaxf(mxA, pvA);
            mnA = fminf(mnA, pvA);
            s1B += pvB;
            s2B = fmaf(pvB, pvB, s2B);
            mxB = fmaxf(mxB, pvB);
            mnB = fminf(mnB, pvB);
        }
        s1A += __shfl_xor(s1A, 32);
        s2A += __shfl_xor(s2A, 32);
        mxA = fmaxf(mxA, __shfl_xor(mxA, 32));
        mnA = fminf(mnA, __shfl_xor(mnA, 32));
        s1B += __shfl_xor(s1B, 32);
        s2B += __shfl_xor(s2B, 32);
        mxB = fmaxf(mxB, __shfl_xor(mxB, 32));
        mnB = fminf(mnB, __shfl_xor(mnB, 32));
        if (h == 0) {
            long bseA = (bNP + nA) * 32 + o;
            float qA = r[bseA];
            mmax[bseA] = mxA + qA;
            mmin[bseA] = mnA + qA;
            atomicAdd(&S1loc[o], s1A + 40.f * qA);
            atomicAdd(&S2loc[o], fmaf(2.f * qA, s1A, fmaf(40.f * qA, qA, s2A)));
            long bseB = (bNP + nB) * 32 + o;
            float qB = r[bseB];
            mmax[bseB] = mxB + qB;
            mmin[bseB] = mnB + qB;
            atomicAdd(&S1loc[o], s1B + 40.f * qB);
            atomicAdd(&S2loc[o], fmaf(2.f * qB, s1B, fmaf(40.f * qB, qB, s2B)));
        }
    }
    __syncthreads();
    if (tid < 32) {
        atomicAdd(&sums[tid], S1loc[tid]);
        atomicAdd(&sums[32 + tid], S2loc[tid]);
    }
}

// ---------------------------------------------------------------------------
// finish: per-channel BN affine from global sums, monotone max/min trick,
// LeakyReLU, residual, write slice of cat into d_out [B][128][N]
// ---------------------------------------------------------------------------
__global__ void finish_kernel(const float* __restrict__ mmax, const float* __restrict__ mmin,
                              const float* __restrict__ sums,
                              const float* __restrict__ g, const float* __restrict__ be,
                              const float* __restrict__ resid,
                              float* __restrict__ outb) {
    int id = blockIdx.x * 256 + threadIdx.x;     // B*32*N = 524288
    int b = id >> 16;
    int o = (id >> 11) & 31;
    int n = id & 2047;
    const float cntf = 655360.0f;                 // B*N*K
    float mean = sums[o] / cntf;
    float var = sums[32 + o] / cntf - mean * mean;
    float sc = g[o] / sqrtf(var + 1e-5f);
    float sh = be[o] - mean * sc;
    long bse = ((long)b * NP + n) * 32 + o;
    float v = (sc >= 0.f) ? mmax[bse] : mmin[bse];
    float y = sc * v + sh;
    y = (y >= 0.f) ? y : 0.2f * y;
    long ob = ((long)b * 128 + o) * NP + n;
    if (resid) y += resid[ob];
    outb[ob] = y;
}

// ---------------------------------------------------------------------------
// final in-place GEMM on d_out: out[b,o,n] = sum_c W5[o,c]*cat[b,c,n]
// ---------------------------------------------------------------------------
__global__ void final_gemm(const float* __restrict__ W5, float* __restrict__ out) {
    __shared__ __align__(16) float catL[128][32];
    int b = blockIdx.x >> 6;
    int n0 = (blockIdx.x & 63) * 32;
    int tid = threadIdx.x;
    for (int i = tid; i < 128 * 32; i += 256) {
        int c = i >> 5, nn = i & 31;
        catL[c][nn] = out[((long)b * 128 + c) * NP + n0 + nn];
    }
    __syncthreads();
    int og = tid >> 3, ng = tid & 7;
    int o0 = og * 4, nl = ng * 4;
    float acc[4][4] = {};
    for (int c = 0; c < 128; c++) {
        float4 cv = *(const float4*)&catL[c][nl];
#pragma unroll
        for (int i = 0; i < 4; i++) {
            float w = W5[(o0 + i) * 128 + c];
            acc[i][0] = fmaf(w, cv.x, acc[i][0]);
            acc[i][1] = fmaf(w, cv.y, acc[i][1]);
            acc[i][2] = fmaf(w, cv.z, acc[i][2]);
            acc[i][3] = fmaf(w, cv.w, acc[i][3]);
        }
    }
#pragma unroll
    for (int i = 0; i < 4; i++) {
        float4 vv = make_float4(acc[i][0], acc[i][1], acc[i][2], acc[i][3]);
        *(float4*)&out[((long)b * 128 + o0 + i) * NP + n0 + nl] = vv;
    }
}

extern "C" void kernel_launch(void* const* d_in, const int* in_sizes, int n_in,
                              void* d_out, int out_size, void* d_ws, size_t ws_size,
                              hipStream_t stream) {
    const float* x  = (const float*)d_in[0];
    const float* W1 = (const float*)d_in[1];
    const float* W2 = (const float*)d_in[2];
    const float* W3 = (const float*)d_in[3];
    const float* W4 = (const float*)d_in[4];
    const float* W5 = (const float*)d_in[5];
    const float* g1 = (const float*)d_in[6];
    const float* b1 = (const float*)d_in[7];
    const float* g2 = (const float*)d_in[8];
    const float* b2 = (const float*)d_in[9];
    const float* g3 = (const float*)d_in[10];
    const float* b3 = (const float*)d_in[11];
    const float* g4 = (const float*)d_in[12];
    const float* b4 = (const float*)d_in[13];
    float* out = (float*)d_out;
    float* ws  = (float*)d_ws;
    // ws layout (floats): p | r | mmax | mmin | xx | sums | XT
    float* p    = ws;
    float* r    = ws + 524288;
    float* mmax = ws + 1048576;
    float* mmin = ws + 1572864;
    float* xx   = ws + 2097152;
    float* sums = ws + 2113536;
    float* XT   = ws + 2113792;   // up to 8*2048*36 = 589824 floats
    hipMemsetAsync(sums, 0, 256 * sizeof(float), stream);

    // block 1 (C=9, CP=12, CPX=16)
    prep_kernel<9, 12, 16><<<2048, 256, 0, stream>>>(x, 9L * NP, W1, p, r, xx, XT);
    knn_kernel<9, 12, 16><<<2048, 256, 0, stream>>>(x, 9L * NP, p, r, xx, XT, mmax, mmin, sums);
    finish_kernel<<<2048, 256, 0, stream>>>(mmax, mmin, sums, g1, b1, nullptr, out);
    // block 2 (C=32, CP=32, CPX=36)
    const float* x1 = out;
    prep_kernel<32, 32, 36><<<2048, 256, 0, stream>>>(x1, 128L * NP, W2, p, r, xx, XT);
    knn_kernel<32, 32, 36><<<2048, 256, 0, stream>>>(x1, 128L * NP, p, r, xx, XT, mmax, mmin, sums + 64);
    finish_kernel<<<2048, 256, 0, stream>>>(mmax, mmin, sums + 64, g2, b2, x1, out + 32 * NP);
    // block 3
    const float* x2 = out + 32 * NP;
    prep_kernel<32, 32, 36><<<2048, 256, 0, stream>>>(x2, 128L * NP, W3, p, r, xx, XT);
    knn_kernel<32, 32, 36><<<2048, 256, 0, stream>>>(x2, 128L * NP, p, r, xx, XT, mmax, mmin, sums + 128);
    finish_kernel<<<2048, 256, 0, stream>>>(mmax, mmin, sums + 128, g3, b3, x2, out + 64 * NP);
    // block 4
    const float* x3 = out + 64 * NP;
    prep_kernel<32, 32, 36><<<2048, 256, 0, stream>>>(x3, 128L * NP, W4, p, r, xx, XT);
    knn_kernel<32, 32, 36><<<2048, 256, 0, stream>>>(x3, 128L * NP, p, r, xx, XT, mmax, mmin, sums + 192);
    finish_kernel<<<2048, 256, 0, stream>>>(mmax, mmin, sums + 192, g4, b4, x3, out + 96 * NP);

    final_gemm<<<512, 256, 0, stream>>>(W5, out);
}

// Round 6
// 606.135 us; speedup vs baseline: 1.4090x; 1.1267x over previous
//
#include <hip/hip_runtime.h>
#include <stdint.h>

#define NP 2048
#define KNN 40
#define CAP 128          // candidate buffer per row (2 slots of 64, int — proven type)

__device__ __forceinline__ unsigned fOrd(float f) {
    unsigned u = __float_as_uint(f);
    return u ^ ((unsigned)((int)u >> 31) | 0x80000000u);
}
__device__ __forceinline__ unsigned long long dOrd(double d) {
    unsigned long long u = (unsigned long long)__double_as_longlong(d);
    return u ^ (((unsigned long long)((long long)u >> 63)) | 0x8000000000000000ull);
}

// ---------------------------------------------------------------------------
// prep: per point: xx = sum x^2 (fp32), p[o] = Wd[o,:]·x, r[o] = (Wc-Wd)[o,:]·x,
// XT[b][n][0..CP) = x (point-contiguous, zero-padded) + fp64 norm at offset CP
// (sequential c-order — must match refine's usage).
// ---------------------------------------------------------------------------
template<int C, int CP, int CPX>
__global__ void prep_kernel(const float* __restrict__ X, long bstride,
                            const float* __restrict__ W,
                            float* __restrict__ p, float* __restrict__ r,
                            float* __restrict__ xx, float* __restrict__ XT) {
    __shared__ float wdT[C][32];
    __shared__ float wrT[C][32];
    int tid = threadIdx.x;
    for (int i = tid; i < 32 * C; i += 256) {
        int o = i / C, c = i - o * C;
        float wd = W[o * 2 * C + c];
        float wc = W[o * 2 * C + C + c];
        wdT[c][o] = wd;
        wrT[c][o] = wc - wd;
    }
    __syncthreads();
    int lane = tid & 63;
    int o = lane & 31;
    int h = lane >> 5;
    int wv = tid >> 6;
    int flat = blockIdx.x * 8 + wv * 2 + h;   // 2048 wgs * 8 points = B*N
    int b = flat >> 11, n = flat & 2047;
    const float* Xb = X + (long)b * bstride + n;
    float pacc = 0.f, racc = 0.f, xxa = 0.f, xto = 0.f;
    double xxd = 0.0;
#pragma unroll
    for (int c = 0; c < C; c++) {
        float xv = Xb[(long)c * NP];
        pacc = fmaf(wdT[c][o], xv, pacc);
        racc = fmaf(wrT[c][o], xv, racc);
        xxa += xv * xv;
        xxd += (double)xv * (double)xv;       // sequential c order (refine-consistent)
        if (c == o) xto = xv;
    }
    long base = ((long)b * NP + n) * 32 + o;
    p[base] = pacc;
    r[base] = racc;
    long rowb = ((long)b * NP + n) * CPX;
    if (o < CP) XT[rowb + o] = (o < C) ? xto : 0.f;
    if (o == 0) {
        xx[b * NP + n] = xxa;
        *reinterpret_cast<double*>(&XT[rowb + CP]) = xxd;
    }
}

// ---------------------------------------------------------------------------
// knn: per (b,n) row. Proven rules R2-R18 retained. R17: paired-row select.
// R20: in-register bitonic rank select (WIN, -45us total).
// R21 (resubmit — R5 bench was a container-infra failure, kernel audited
// for OOB/hang/LDS-limit and clean): 8 waves/block (512 thr), 16 rows per
// block, grid 1024. Rationale: VALUBusy 30% / occupancy ~29% with per-wave
// VALU ~11k cyc -> 70% of wall is latency stall with only 16 waves/CU
// resident (LDS-capped). 512-thr blocks: staging per row HALVES, LDS/block
// ~46.9KB -> 3 blocks * 8 waves = 24 waves/CU resident (+50% TLP). The
// per-wave select/refine/sort/gather code is byte-identical (intra-wave
// ops only); only block geometry and LDS array dims change. VGPR must
// stay <=85 for 6 waves/SIMD (currently 80; NO prefetch regs this round).
// wg = 512 = 8 waves; each wave owns 2 rows; 1024 wgs (128 per batch).
// ---------------------------------------------------------------------------
template<int C, int CP, int CPX>
__global__ __launch_bounds__(512, 2)
void knn_kernel(const float* __restrict__ X, long bstride,
                const float* __restrict__ p, const float* __restrict__ r,
                const float* __restrict__ xx, const float* __restrict__ XT,
                float* __restrict__ mmax, float* __restrict__ mmin,
                float* __restrict__ sums) {
    __shared__ __align__(16) float xt[2][C * 128]; // two 128-tiles per round
    __shared__ __align__(16) float xxt[256];
    __shared__ __align__(8) float qld[8][CP][2];   // [wave][c][rowA/rowB]
    __shared__ int sel[16][KNN];
    __shared__ int cand[16][CAP];
    __shared__ float S1loc[32], S2loc[32];
    int tid = threadIdx.x;
    if (tid < 32) { S1loc[tid] = 0.f; S2loc[tid] = 0.f; }
    for (int i = tid; i < 16 * KNN; i += 512) ((int*)sel)[i] = 0;   // defensive init
    int lane = tid & 63;
    int wv = tid >> 6;                    // 0..7
    int half = lane >> 5;                 // which of the 2 staged tiles
    int l32 = lane & 31;
    int b = blockIdx.x >> 7;              // 128 wgs per batch
    int n0 = (blockIdx.x & 127) * 16;
    int nA = n0 + wv * 2, nB = nA + 1;
    int rowA = wv * 2, rowB = rowA + 1;   // 0..15
    const float* Xb = X + (long)b * bstride;
    const float* XTb = XT + (long)b * NP * CPX;
    long bNP = (long)b * NP;

    // queries -> LDS (wave-private rows; barrier below covers visibility)
    if (lane < CP) {
        qld[wv][lane][0] = XTb[(long)nA * CPX + lane];
        qld[wv][lane][1] = XTb[(long)nB * CPX + lane];
    }
    float xxnA = xx[bNP + nA];
    float xxnB = xx[bNP + nB];

    unsigned uA[16], uB[16];   // 16-bit keys packed 2/reg; slot 2*t2+s, s=j>>1
    for (int t2 = 0; t2 < 8; t2++) {
        __syncthreads();
        // stage tiles 2*t2 (->xt[0]) and 2*t2+1 (->xt[1]); R10 staging pattern
        for (int i = tid; i < C * 64; i += 512) {
            int c = i >> 6, g = i & 63;
            int tt = g >> 5, gg = g & 31;
            *(float4*)&xt[tt][c * 128 + gg * 4] =
                *(const float4*)&Xb[(long)c * NP + (t2 * 2 + tt) * 128 + gg * 4];
        }
        if (tid < 256) xxt[tid] = xx[bNP + t2 * 256 + tid];
        __syncthreads();
        const float* xth = xt[half];
        float4 ia = make_float4(0.f, 0.f, 0.f, 0.f);
        float4 ib = make_float4(0.f, 0.f, 0.f, 0.f);
#pragma unroll
        for (int c = 0; c < C; c++) {
            float2 q = *(const float2*)&qld[wv][c][0];      // b64 broadcast
            float4 xv = *(const float4*)&xth[c * 128 + 4 * l32]; // ONE b128/c
            ia.x = fmaf(q.x, xv.x, ia.x);
            ia.y = fmaf(q.x, xv.y, ia.y);
            ia.z = fmaf(q.x, xv.z, ia.z);
            ia.w = fmaf(q.x, xv.w, ia.w);
            ib.x = fmaf(q.y, xv.x, ib.x);
            ib.y = fmaf(q.y, xv.y, ib.y);
            ib.z = fmaf(q.y, xv.z, ib.z);
            ib.w = fmaf(q.y, xv.w, ib.w);
        }
        float4 xm = *(const float4*)&xxt[half * 128 + 4 * l32];
        unsigned a0 = fOrd((xxnA - 2.0f * ia.x) + xm.x) >> 16;   // ref rounding
        unsigned a1 = fOrd((xxnA - 2.0f * ia.y) + xm.y) >> 16;
        unsigned a2 = fOrd((xxnA - 2.0f * ia.z) + xm.z) >> 16;
        unsigned a3 = fOrd((xxnA - 2.0f * ia.w) + xm.w) >> 16;
        unsigned b0 = fOrd((xxnB - 2.0f * ib.x) + xm.x) >> 16;
        unsigned b1 = fOrd((xxnB - 2.0f * ib.y) + xm.y) >> 16;
        unsigned b2_ = fOrd((xxnB - 2.0f * ib.z) + xm.z) >> 16;
        unsigned b3 = fOrd((xxnB - 2.0f * ib.w) + xm.w) >> 16;
        uA[2 * t2]     = (a1 << 16) | a0;
        uA[2 * t2 + 1] = (a3 << 16) | a2;
        uB[2 * t2]     = (b1 << 16) | b0;
        uB[2 * t2 + 1] = (b3 << 16) | b2_;
    }

    unsigned long long lmlt = (1ull << lane) - 1ull;

    // hoist f64 self-norms (independent global loads, hide under select)
    double xxdA = *reinterpret_cast<const double*>(&XTb[(long)nA * CPX + CP]);
    double xxdB = *reinterpret_cast<const double*>(&XTb[(long)nB * CPX + CP]);

    // --- pass 1 select, BOTH rows: fixed 16-step bitwise rank-40 select ---
    unsigned vA = 0u, vB = 0u;
    for (int bit = 15; bit >= 0; bit--) {
        unsigned tA = vA | ((1u << bit) - 1u);
        unsigned tB = vB | ((1u << bit) - 1u);
        int cA = 0, cB = 0;
#pragma unroll
        for (int t = 0; t < 16; t++) {
            cA += __popcll(__ballot((uA[t] & 0xFFFFu) <= tA));
            cA += __popcll(__ballot((uA[t] >> 16) <= tA));
            cB += __popcll(__ballot((uB[t] & 0xFFFFu) <= tB));
            cB += __popcll(__ballot((uB[t] >> 16) <= tB));
        }
        if (cA < KNN) vA |= (1u << bit);
        if (cB < KNN) vB |= (1u << bit);
    }
    unsigned thrA = (vA > 0xFFFEu) ? 0xFFFFu : vA + 1u;   // +1 bucket (proven)
    unsigned thrB = (vB > 0xFFFEu) ? 0xFFFFu : vB + 1u;

    // --- candidate lists, BOTH rows (m = t2*256 + half*128 + 4*l32 + j) ---
    int baseA = 0, baseB = 0;
#pragma unroll
    for (int kk = 0; kk < 16; kk++) {
#pragma unroll
        for (int hh = 0; hh < 2; hh++) {
            unsigned kA = hh ? (uA[kk] >> 16) : (uA[kk] & 0xFFFFu);
            unsigned kB = hh ? (uB[kk] >> 16) : (uB[kk] & 0xFFFFu);
            int idx = (kk >> 1) * 256 + half * 128 + 4 * l32 + (kk & 1) * 2 + hh;
            bool pA = (kA <= thrA), pB = (kB <= thrB);
            unsigned long long mkA = __ballot(pA), mkB = __ballot(pB);
            if (pA) {
                int pos = baseA + __popcll(mkA & lmlt);
                if (pos < CAP) cand[rowA][pos] = idx;
            }
            if (pB) {
                int pos = baseB + __popcll(mkB & lmlt);
                if (pos < CAP) cand[rowB][pos] = idx;
            }
            baseA += __popcll(mkA);
            baseB += __popcll(mkB);
        }
    }
    int cntA = baseA < CAP ? baseA : CAP;
    int cntB = baseB < CAP ? baseB : CAP;

    // --- refine candidates in float64, BOTH rows (exact order preserved) ---
    unsigned long long keyA[CAP / 64], keyB[CAP / 64];
    int mixA[CAP / 64], mixB[CAP / 64];
#pragma unroll
    for (int s3 = 0; s3 < CAP / 64; s3++) {
        int slot = s3 * 64 + lane;
        keyA[s3] = ~0ull; mixA[s3] = 0;
        keyB[s3] = ~0ull; mixB[s3] = 0;
        if (slot < cntA) {
            int m = cand[rowA][slot] & (NP - 1);   // defensive mask
            mixA[s3] = m;
            const float* xmp = XTb + (long)m * CPX;
            double inner = 0.0;
#pragma unroll
            for (int g = 0; g < CP / 4; g++) {
                float4 v = *(const float4*)&xmp[g * 4];
                inner += (double)qld[wv][g * 4 + 0][0] * (double)v.x;
                inner += (double)qld[wv][g * 4 + 1][0] * (double)v.y;
                inner += (double)qld[wv][g * 4 + 2][0] * (double)v.z;
                inner += (double)qld[wv][g * 4 + 3][0] * (double)v.w;
            }
            double xxm = *reinterpret_cast<const double*>(&xmp[CP]);
            double dd = (xxdA - 2.0 * inner) + xxm;
            keyA[s3] = dOrd(dd);
        }
        if (slot < cntB) {
            int m = cand[rowB][slot] & (NP - 1);   // defensive mask
            mixB[s3] = m;
            const float* xmp = XTb + (long)m * CPX;
            double inner = 0.0;
#pragma unroll
            for (int g = 0; g < CP / 4; g++) {
                float4 v = *(const float4*)&xmp[g * 4];
                inner += (double)qld[wv][g * 4 + 0][1] * (double)v.x;
                inner += (double)qld[wv][g * 4 + 1][1] * (double)v.y;
                inner += (double)qld[wv][g * 4 + 2][1] * (double)v.z;
                inner += (double)qld[wv][g * 4 + 3][1] * (double)v.w;
            }
            double xxm = *reinterpret_cast<const double*>(&xmp[CP]);
            double dd = (xxdB - 2.0 * inner) + xxm;
            keyB[s3] = dOrd(dd);
        }
    }

    // --- R20: rank select via in-register bitonic sort by (key, idx) ---
    // compare-exchange with partner lane^S; keepmin decides which end we keep
    auto cex = [](unsigned long long& k, int& i, const int S, const bool keepmin) {
        unsigned long long pk = __shfl_xor(k, S);
        int pi = __shfl_xor(i, S);
        bool less = (k < pk) || (k == pk && i < pi);
        bool tp = (less != keepmin);
        k = tp ? pk : k;
        i = tp ? pi : i;
    };
    if (cntA <= 64 && cntB <= 64) {
        // 64-element ascending bitonic sort, slot0 only (21 stages)
#pragma unroll
        for (int kk2 = 1; kk2 <= 6; kk2++) {
            const int K = 1 << kk2;
#pragma unroll
            for (int ss = kk2 - 1; ss >= 0; ss--) {
                const int S = 1 << ss;
                bool asc0 = (K == 64) ? true : ((lane & K) == 0);
                bool km0 = ((lane & S) == 0) == asc0;
                cex(keyA[0], mixA[0], S, km0);
                cex(keyB[0], mixB[0], S, km0);
            }
        }
    } else {
        // 128-element ascending bitonic sort, 2 slots/lane (element j = s3*64+lane)
#pragma unroll
        for (int kk2 = 1; kk2 <= 6; kk2++) {
            const int K = 1 << kk2;
#pragma unroll
            for (int ss = kk2 - 1; ss >= 0; ss--) {
                const int S = 1 << ss;
                bool ascL = (lane & K) == 0;
                bool asc0 = (K == 64) ? true  : ascL;   // j&64 = 0 for slot0
                bool asc1 = (K == 64) ? false : ascL;   // j&64 = 64 for slot1
                bool km0 = ((lane & S) == 0) == asc0;
                bool km1 = ((lane & S) == 0) == asc1;
                cex(keyA[0], mixA[0], S, km0);
                cex(keyA[1], mixA[1], S, km1);
                cex(keyB[0], mixB[0], S, km0);
                cex(keyB[1], mixB[1], S, km1);
            }
        }
        // K=128 level. s=64: local exchange between slots (ascending: e0=min)
        {
            bool lA = (keyA[0] < keyA[1]) || (keyA[0] == keyA[1] && mixA[0] < mixA[1]);
            unsigned long long tk = keyA[0]; int ti = mixA[0];
            keyA[0] = lA ? keyA[0] : keyA[1];  mixA[0] = lA ? mixA[0] : mixA[1];
            keyA[1] = lA ? keyA[1] : tk;       mixA[1] = lA ? mixA[1] : ti;
            bool lB = (keyB[0] < keyB[1]) || (keyB[0] == keyB[1] && mixB[0] < mixB[1]);
            tk = keyB[0]; ti = mixB[0];
            keyB[0] = lB ? keyB[0] : keyB[1];  mixB[0] = lB ? mixB[0] : mixB[1];
            keyB[1] = lB ? keyB[1] : tk;       mixB[1] = lB ? mixB[1] : ti;
        }
        // s = 32..1, ascending everywhere (j&128 == 0)
#pragma unroll
        for (int ss = 5; ss >= 0; ss--) {
            const int S = 1 << ss;
            bool km = ((lane & S) == 0);
            cex(keyA[0], mixA[0], S, km);
            cex(keyA[1], mixA[1], S, km);
            cex(keyB[0], mixB[0], S, km);
            cex(keyB[1], mixB[1], S, km);
        }
    }
    // ranks 0..63 now live in slot0 by lane; emit the 40 smallest (key,idx)
    if (lane < KNN) {
        sel[rowA][lane] = mixA[0];
        sel[rowB][lane] = mixB[0];
    }

    // --- fused gather-reduce over the selected 40, BOTH rows ---
    {
        int o = lane & 31, h = lane >> 5;
        float s1A = 0.f, s2A = 0.f, s1B = 0.f, s2B = 0.f;
        float mxA = -__builtin_inff(), mnA = __builtin_inff();
        float mxB = -__builtin_inff(), mnB = __builtin_inff();
        const float* pb = p + bNP * 32 + o;
        for (int k = h * 20; k < h * 20 + 20; k++) {
            int mA = sel[rowA][k] & (NP - 1);          // defensive mask
            int mB = sel[rowB][k] & (NP - 1);
            float pvA = pb[(long)mA * 32];
            float pvB = pb[(long)mB * 32];
            s1A += pvA;
            s2A = fmaf(pvA, pvA, s2A);
            mxA = fmaxf(mxA, pvA);
            mnA = fminf(mnA, pvA);
            s1B += pvB;
            s2B = fmaf(pvB, pvB, s2B);
            mxB = fmaxf(mxB, pvB);
            mnB = fminf(mnB, pvB);
        }
        s1A += __shfl_xor(s1A, 32);
        s2A += __shfl_xor(s2A, 32);
        mxA = fmaxf(mxA, __shfl_xor(mxA, 32));
        mnA = fminf(mnA, __shfl_xor(mnA, 32));
        s1B += __shfl_xor(s1B, 32);
        s2B += __shfl_xor(s2B, 32);
        mxB = fmaxf(mxB, __shfl_xor(mxB, 32));
        mnB = fminf(mnB, __shfl_xor(mnB, 32));
        if (h == 0) {
            long bseA = (bNP + nA) * 32 + o;
            float qA = r[bseA];
            mmax[bseA] = mxA + qA;
            mmin[bseA] = mnA + qA;
            atomicAdd(&S1loc[o], s1A + 40.f * qA);
            atomicAdd(&S2loc[o], fmaf(2.f * qA, s1A, fmaf(40.f * qA, qA, s2A)));
            long bseB = (bNP + nB) * 32 + o;
            float qB = r[bseB];
            mmax[bseB] = mxB + qB;
            mmin[bseB] = mnB + qB;
            atomicAdd(&S1loc[o], s1B + 40.f * qB);
            atomicAdd(&S2loc[o], fmaf(2.f * qB, s1B, fmaf(40.f * qB, qB, s2B)));
        }
    }
    __syncthreads();
    if (tid < 32) {
        atomicAdd(&sums[tid], S1loc[tid]);
        atomicAdd(&sums[32 + tid], S2loc[tid]);
    }
}

// ---------------------------------------------------------------------------
// finish: per-channel BN affine from global sums, monotone max/min trick,
// LeakyReLU, residual, write slice of cat into d_out [B][128][N]
// ---------------------------------------------------------------------------
__global__ void finish_kernel(const float* __restrict__ mmax, const float* __restrict__ mmin,
                              const float* __restrict__ sums,
                              const float* __restrict__ g, const float* __restrict__ be,
                              const float* __restrict__ resid,
                              float* __restrict__ outb) {
    int id = blockIdx.x * 256 + threadIdx.x;     // B*32*N = 524288
    int b = id >> 16;
    int o = (id >> 11) & 31;
    int n = id & 2047;
    const float cntf = 655360.0f;                 // B*N*K
    float mean = sums[o] / cntf;
    float var = sums[32 + o] / cntf - mean * mean;
    float sc = g[o] / sqrtf(var + 1e-5f);
    float sh = be[o] - mean * sc;
    long bse = ((long)b * NP + n) * 32 + o;
    float v = (sc >= 0.f) ? mmax[bse] : mmin[bse];
    float y = sc * v + sh;
    y = (y >= 0.f) ? y : 0.2f * y;
    long ob = ((long)b * 128 + o) * NP + n;
    if (resid) y += resid[ob];
    outb[ob] = y;
}

// ---------------------------------------------------------------------------
// final in-place GEMM on d_out: out[b,o,n] = sum_c W5[o,c]*cat[b,c,n]
// ---------------------------------------------------------------------------
__global__ void final_gemm(const float* __restrict__ W5, float* __restrict__ out) {
    __shared__ __align__(16) float catL[128][32];
    int b = blockIdx.x >> 6;
    int n0 = (blockIdx.x & 63) * 32;
    int tid = threadIdx.x;
    for (int i = tid; i < 128 * 32; i += 256) {
        int c = i >> 5, nn = i & 31;
        catL[c][nn] = out[((long)b * 128 + c) * NP + n0 + nn];
    }
    __syncthreads();
    int og = tid >> 3, ng = tid & 7;
    int o0 = og * 4, nl = ng * 4;
    float acc[4][4] = {};
    for (int c = 0; c < 128; c++) {
        float4 cv = *(const float4*)&catL[c][nl];
#pragma unroll
        for (int i = 0; i < 4; i++) {
            float w = W5[(o0 + i) * 128 + c];
            acc[i][0] = fmaf(w, cv.x, acc[i][0]);
            acc[i][1] = fmaf(w, cv.y, acc[i][1]);
            acc[i][2] = fmaf(w, cv.z, acc[i][2]);
            acc[i][3] = fmaf(w, cv.w, acc[i][3]);
        }
    }
#pragma unroll
    for (int i = 0; i < 4; i++) {
        float4 vv = make_float4(acc[i][0], acc[i][1], acc[i][2], acc[i][3]);
        *(float4*)&out[((long)b * 128 + o0 + i) * NP + n0 + nl] = vv;
    }
}

extern "C" void kernel_launch(void* const* d_in, const int* in_sizes, int n_in,
                              void* d_out, int out_size, void* d_ws, size_t ws_size,
                              hipStream_t stream) {
    const float* x  = (const float*)d_in[0];
    const float* W1 = (const float*)d_in[1];
    const float* W2 = (const float*)d_in[2];
    const float* W3 = (const float*)d_in[3];
    const float* W4 = (const float*)d_in[4];
    const float* W5 = (const float*)d_in[5];
    const float* g1 = (const float*)d_in[6];
    const float* b1 = (const float*)d_in[7];
    const float* g2 = (const float*)d_in[8];
    const float* b2 = (const float*)d_in[9];
    const float* g3 = (const float*)d_in[10];
    const float* b3 = (const float*)d_in[11];
    const float* g4 = (const float*)d_in[12];
    const float* b4 = (const float*)d_in[13];
    float* out = (float*)d_out;
    float* ws  = (float*)d_ws;
    // ws layout (floats): p | r | mmax | mmin | xx | sums | XT
    float* p    = ws;
    float* r    = ws + 524288;
    float* mmax = ws + 1048576;
    float* mmin = ws + 1572864;
    float* xx   = ws + 2097152;
    float* sums = ws + 2113536;
    float* XT   = ws + 2113792;   // up to 8*2048*36 = 589824 floats
    hipMemsetAsync(sums, 0, 256 * sizeof(float), stream);

    // block 1 (C=9, CP=12, CPX=16)
    prep_kernel<9, 12, 16><<<2048, 256, 0, stream>>>(x, 9L * NP, W1, p, r, xx, XT);
    knn_kernel<9, 12, 16><<<1024, 512, 0, stream>>>(x, 9L * NP, p, r, xx, XT, mmax, mmin, sums);
    finish_kernel<<<2048, 256, 0, stream>>>(mmax, mmin, sums, g1, b1, nullptr, out);
    // block 2 (C=32, CP=32, CPX=36)
    const float* x1 = out;
    prep_kernel<32, 32, 36><<<2048, 256, 0, stream>>>(x1, 128L * NP, W2, p, r, xx, XT);
    knn_kernel<32, 32, 36><<<1024, 512, 0, stream>>>(x1, 128L * NP, p, r, xx, XT, mmax, mmin, sums + 64);
    finish_kernel<<<2048, 256, 0, stream>>>(mmax, mmin, sums + 64, g2, b2, x1, out + 32 * NP);
    // block 3
    const float* x2 = out + 32 * NP;
    prep_kernel<32, 32, 36><<<2048, 256, 0, stream>>>(x2, 128L * NP, W3, p, r, xx, XT);
    knn_kernel<32, 32, 36><<<1024, 512, 0, stream>>>(x2, 128L * NP, p, r, xx, XT, mmax, mmin, sums + 128);
    finish_kernel<<<2048, 256, 0, stream>>>(mmax, mmin, sums + 128, g3, b3, x2, out + 64 * NP);
    // block 4
    const float* x3 = out + 64 * NP;
    prep_kernel<32, 32, 36><<<2048, 256, 0, stream>>>(x3, 128L * NP, W4, p, r, xx, XT);
    knn_kernel<32, 32, 36><<<1024, 512, 0, stream>>>(x3, 128L * NP, p, r, xx, XT, mmax, mmin, sums + 192);
    finish_kernel<<<2048, 256, 0, stream>>>(mmax, mmin, sums + 192, g4, b4, x3, out + 96 * NP);

    final_gemm<<<512, 256, 0, stream>>>(W5, out);
}

// Round 7
// 604.979 us; speedup vs baseline: 1.4117x; 1.0019x over previous
//
#include <hip/hip_runtime.h>
#include <stdint.h>

#define NP 2048
#define KNN 40
#define CAP 128          // candidate buffer per row (2 slots of 64, int — proven type)

__device__ __forceinline__ unsigned fOrd(float f) {
    unsigned u = __float_as_uint(f);
    return u ^ ((unsigned)((int)u >> 31) | 0x80000000u);
}
__device__ __forceinline__ unsigned long long dOrd(double d) {
    unsigned long long u = (unsigned long long)__double_as_longlong(d);
    return u ^ (((unsigned long long)((long long)u >> 63)) | 0x8000000000000000ull);
}

// ---------------------------------------------------------------------------
// prep: per point: xx = sum x^2 (fp32), p[o] = Wd[o,:]·x, r[o] = (Wc-Wd)[o,:]·x,
// XT[b][n][0..CP) = x (point-contiguous, zero-padded) + fp64 norm at offset CP
// (sequential c-order — must match refine's usage).
// ---------------------------------------------------------------------------
template<int C, int CP, int CPX>
__global__ void prep_kernel(const float* __restrict__ X, long bstride,
                            const float* __restrict__ W,
                            float* __restrict__ p, float* __restrict__ r,
                            float* __restrict__ xx, float* __restrict__ XT) {
    __shared__ float wdT[C][32];
    __shared__ float wrT[C][32];
    int tid = threadIdx.x;
    for (int i = tid; i < 32 * C; i += 256) {
        int o = i / C, c = i - o * C;
        float wd = W[o * 2 * C + c];
        float wc = W[o * 2 * C + C + c];
        wdT[c][o] = wd;
        wrT[c][o] = wc - wd;
    }
    __syncthreads();
    int lane = tid & 63;
    int o = lane & 31;
    int h = lane >> 5;
    int wv = tid >> 6;
    int flat = blockIdx.x * 8 + wv * 2 + h;   // 2048 wgs * 8 points = B*N
    int b = flat >> 11, n = flat & 2047;
    const float* Xb = X + (long)b * bstride + n;
    float pacc = 0.f, racc = 0.f, xxa = 0.f, xto = 0.f;
    double xxd = 0.0;
#pragma unroll
    for (int c = 0; c < C; c++) {
        float xv = Xb[(long)c * NP];
        pacc = fmaf(wdT[c][o], xv, pacc);
        racc = fmaf(wrT[c][o], xv, racc);
        xxa += xv * xv;
        xxd += (double)xv * (double)xv;       // sequential c order (refine-consistent)
        if (c == o) xto = xv;
    }
    long base = ((long)b * NP + n) * 32 + o;
    p[base] = pacc;
    r[base] = racc;
    long rowb = ((long)b * NP + n) * CPX;
    if (o < CP) XT[rowb + o] = (o < C) ? xto : 0.f;
    if (o == 0) {
        xx[b * NP + n] = xxa;
        *reinterpret_cast<double*>(&XT[rowb + CP]) = xxd;
    }
}

// ---------------------------------------------------------------------------
// knn: per (b,n) row. Proven rules R2-R18 retained. R17: paired-row select.
// R20: in-register bitonic rank select (WIN). R21: 8 waves/512 thr (WIN:
// 180->127us, VALUBusy 44%, occ 40%).
// R22 (this round): LDS ALIASING for 4 blocks/CU. xt (32KB, dead after the
// distance loop) and cand+sel (10.5KB, born after it) share one union
// region; one extra __syncthreads() separates the lifetimes. LDS 47.1 ->
// ~36.1KB -> 4 blocks * 8 waves = 32 waves/CU (full wave-slot occupancy,
// +33% TLP over R21's 24). sel defensive init dropped — bitonic emission
// writes all 40 slots unconditionally (lane<KNN). All math byte-identical.
// wg = 512 = 8 waves; each wave owns 2 rows; 1024 wgs (128 per batch).
// ---------------------------------------------------------------------------
template<int C, int CP, int CPX>
__global__ __launch_bounds__(512, 2)
void knn_kernel(const float* __restrict__ X, long bstride,
                const float* __restrict__ p, const float* __restrict__ r,
                const float* __restrict__ xx, const float* __restrict__ XT,
                float* __restrict__ mmax, float* __restrict__ mmin,
                float* __restrict__ sums) {
    // union region: xt[2][C*128] (distance phase)  OR  cand[16][CAP]+sel[16][KNN]
    constexpr int XT_FLOATS = 2 * C * 128;
    constexpr int CS_FLOATS = 16 * CAP + 16 * KNN;
    constexpr int UNI_FLOATS = (XT_FLOATS > CS_FLOATS) ? XT_FLOATS : CS_FLOATS;
    __shared__ __align__(16) float uni[UNI_FLOATS];
    __shared__ __align__(16) float xxt[256];
    __shared__ __align__(8) float qld[8][CP][2];   // [wave][c][rowA/rowB]
    __shared__ float S1loc[32], S2loc[32];
    int* candb = (int*)uni;               // valid after post-distance barrier
    int* selb  = (int*)uni + 16 * CAP;
    int tid = threadIdx.x;
    if (tid < 32) { S1loc[tid] = 0.f; S2loc[tid] = 0.f; }
    int lane = tid & 63;
    int wv = tid >> 6;                    // 0..7
    int half = lane >> 5;                 // which of the 2 staged tiles
    int l32 = lane & 31;
    int b = blockIdx.x >> 7;              // 128 wgs per batch
    int n0 = (blockIdx.x & 127) * 16;
    int nA = n0 + wv * 2, nB = nA + 1;
    int rowA = wv * 2, rowB = rowA + 1;   // 0..15
    const float* Xb = X + (long)b * bstride;
    const float* XTb = XT + (long)b * NP * CPX;
    long bNP = (long)b * NP;

    // queries -> LDS (wave-private rows; barrier below covers visibility)
    if (lane < CP) {
        qld[wv][lane][0] = XTb[(long)nA * CPX + lane];
        qld[wv][lane][1] = XTb[(long)nB * CPX + lane];
    }
    float xxnA = xx[bNP + nA];
    float xxnB = xx[bNP + nB];

    unsigned uA[16], uB[16];   // 16-bit keys packed 2/reg; slot 2*t2+s, s=j>>1
    for (int t2 = 0; t2 < 8; t2++) {
        __syncthreads();
        // stage tiles 2*t2 (->xt half 0) and 2*t2+1 (->half 1); R10 pattern
        for (int i = tid; i < C * 64; i += 512) {
            int c = i >> 6, g = i & 63;
            int tt = g >> 5, gg = g & 31;
            *(float4*)&uni[tt * (C * 128) + c * 128 + gg * 4] =
                *(const float4*)&Xb[(long)c * NP + (t2 * 2 + tt) * 128 + gg * 4];
        }
        if (tid < 256) xxt[tid] = xx[bNP + t2 * 256 + tid];
        __syncthreads();
        const float* xth = uni + half * (C * 128);
        float4 ia = make_float4(0.f, 0.f, 0.f, 0.f);
        float4 ib = make_float4(0.f, 0.f, 0.f, 0.f);
#pragma unroll
        for (int c = 0; c < C; c++) {
            float2 q = *(const float2*)&qld[wv][c][0];      // b64 broadcast
            float4 xv = *(const float4*)&xth[c * 128 + 4 * l32]; // ONE b128/c
            ia.x = fmaf(q.x, xv.x, ia.x);
            ia.y = fmaf(q.x, xv.y, ia.y);
            ia.z = fmaf(q.x, xv.z, ia.z);
            ia.w = fmaf(q.x, xv.w, ia.w);
            ib.x = fmaf(q.y, xv.x, ib.x);
            ib.y = fmaf(q.y, xv.y, ib.y);
            ib.z = fmaf(q.y, xv.z, ib.z);
            ib.w = fmaf(q.y, xv.w, ib.w);
        }
        float4 xm = *(const float4*)&xxt[half * 128 + 4 * l32];
        unsigned a0 = fOrd((xxnA - 2.0f * ia.x) + xm.x) >> 16;   // ref rounding
        unsigned a1 = fOrd((xxnA - 2.0f * ia.y) + xm.y) >> 16;
        unsigned a2 = fOrd((xxnA - 2.0f * ia.z) + xm.z) >> 16;
        unsigned a3 = fOrd((xxnA - 2.0f * ia.w) + xm.w) >> 16;
        unsigned b0 = fOrd((xxnB - 2.0f * ib.x) + xm.x) >> 16;
        unsigned b1 = fOrd((xxnB - 2.0f * ib.y) + xm.y) >> 16;
        unsigned b2_ = fOrd((xxnB - 2.0f * ib.z) + xm.z) >> 16;
        unsigned b3 = fOrd((xxnB - 2.0f * ib.w) + xm.w) >> 16;
        uA[2 * t2]     = (a1 << 16) | a0;
        uA[2 * t2 + 1] = (a3 << 16) | a2;
        uB[2 * t2]     = (b1 << 16) | b0;
        uB[2 * t2 + 1] = (b3 << 16) | b2_;
    }
    // lifetime switch: all waves done reading xt before cand/sel writes
    __syncthreads();

    unsigned long long lmlt = (1ull << lane) - 1ull;

    // hoist f64 self-norms (independent global loads, hide under select)
    double xxdA = *reinterpret_cast<const double*>(&XTb[(long)nA * CPX + CP]);
    double xxdB = *reinterpret_cast<const double*>(&XTb[(long)nB * CPX + CP]);

    // --- pass 1 select, BOTH rows: fixed 16-step bitwise rank-40 select ---
    unsigned vA = 0u, vB = 0u;
    for (int bit = 15; bit >= 0; bit--) {
        unsigned tA = vA | ((1u << bit) - 1u);
        unsigned tB = vB | ((1u << bit) - 1u);
        int cA = 0, cB = 0;
#pragma unroll
        for (int t = 0; t < 16; t++) {
            cA += __popcll(__ballot((uA[t] & 0xFFFFu) <= tA));
            cA += __popcll(__ballot((uA[t] >> 16) <= tA));
            cB += __popcll(__ballot((uB[t] & 0xFFFFu) <= tB));
            cB += __popcll(__ballot((uB[t] >> 16) <= tB));
        }
        if (cA < KNN) vA |= (1u << bit);
        if (cB < KNN) vB |= (1u << bit);
    }
    unsigned thrA = (vA > 0xFFFEu) ? 0xFFFFu : vA + 1u;   // +1 bucket (proven)
    unsigned thrB = (vB > 0xFFFEu) ? 0xFFFFu : vB + 1u;

    // --- candidate lists, BOTH rows (m = t2*256 + half*128 + 4*l32 + j) ---
    int baseA = 0, baseB = 0;
#pragma unroll
    for (int kk = 0; kk < 16; kk++) {
#pragma unroll
        for (int hh = 0; hh < 2; hh++) {
            unsigned kA = hh ? (uA[kk] >> 16) : (uA[kk] & 0xFFFFu);
            unsigned kB = hh ? (uB[kk] >> 16) : (uB[kk] & 0xFFFFu);
            int idx = (kk >> 1) * 256 + half * 128 + 4 * l32 + (kk & 1) * 2 + hh;
            bool pA = (kA <= thrA), pB = (kB <= thrB);
            unsigned long long mkA = __ballot(pA), mkB = __ballot(pB);
            if (pA) {
                int pos = baseA + __popcll(mkA & lmlt);
                if (pos < CAP) candb[rowA * CAP + pos] = idx;
            }
            if (pB) {
                int pos = baseB + __popcll(mkB & lmlt);
                if (pos < CAP) candb[rowB * CAP + pos] = idx;
            }
            baseA += __popcll(mkA);
            baseB += __popcll(mkB);
        }
    }
    int cntA = baseA < CAP ? baseA : CAP;
    int cntB = baseB < CAP ? baseB : CAP;

    // --- refine candidates in float64, BOTH rows (exact order preserved) ---
    unsigned long long keyA[CAP / 64], keyB[CAP / 64];
    int mixA[CAP / 64], mixB[CAP / 64];
#pragma unroll
    for (int s3 = 0; s3 < CAP / 64; s3++) {
        int slot = s3 * 64 + lane;
        keyA[s3] = ~0ull; mixA[s3] = 0;
        keyB[s3] = ~0ull; mixB[s3] = 0;
        if (slot < cntA) {
            int m = candb[rowA * CAP + slot] & (NP - 1);   // defensive mask
            mixA[s3] = m;
            const float* xmp = XTb + (long)m * CPX;
            double inner = 0.0;
#pragma unroll
            for (int g = 0; g < CP / 4; g++) {
                float4 v = *(const float4*)&xmp[g * 4];
                inner += (double)qld[wv][g * 4 + 0][0] * (double)v.x;
                inner += (double)qld[wv][g * 4 + 1][0] * (double)v.y;
                inner += (double)qld[wv][g * 4 + 2][0] * (double)v.z;
                inner += (double)qld[wv][g * 4 + 3][0] * (double)v.w;
            }
            double xxm = *reinterpret_cast<const double*>(&xmp[CP]);
            double dd = (xxdA - 2.0 * inner) + xxm;
            keyA[s3] = dOrd(dd);
        }
        if (slot < cntB) {
            int m = candb[rowB * CAP + slot] & (NP - 1);   // defensive mask
            mixB[s3] = m;
            const float* xmp = XTb + (long)m * CPX;
            double inner = 0.0;
#pragma unroll
            for (int g = 0; g < CP / 4; g++) {
                float4 v = *(const float4*)&xmp[g * 4];
                inner += (double)qld[wv][g * 4 + 0][1] * (double)v.x;
                inner += (double)qld[wv][g * 4 + 1][1] * (double)v.y;
                inner += (double)qld[wv][g * 4 + 2][1] * (double)v.z;
                inner += (double)qld[wv][g * 4 + 3][1] * (double)v.w;
            }
            double xxm = *reinterpret_cast<const double*>(&xmp[CP]);
            double dd = (xxdB - 2.0 * inner) + xxm;
            keyB[s3] = dOrd(dd);
        }
    }

    // --- R20: rank select via in-register bitonic sort by (key, idx) ---
    // compare-exchange with partner lane^S; keepmin decides which end we keep
    auto cex = [](unsigned long long& k, int& i, const int S, const bool keepmin) {
        unsigned long long pk = __shfl_xor(k, S);
        int pi = __shfl_xor(i, S);
        bool less = (k < pk) || (k == pk && i < pi);
        bool tp = (less != keepmin);
        k = tp ? pk : k;
        i = tp ? pi : i;
    };
    if (cntA <= 64 && cntB <= 64) {
        // 64-element ascending bitonic sort, slot0 only (21 stages)
#pragma unroll
        for (int kk2 = 1; kk2 <= 6; kk2++) {
            const int K = 1 << kk2;
#pragma unroll
            for (int ss = kk2 - 1; ss >= 0; ss--) {
                const int S = 1 << ss;
                bool asc0 = (K == 64) ? true : ((lane & K) == 0);
                bool km0 = ((lane & S) == 0) == asc0;
                cex(keyA[0], mixA[0], S, km0);
                cex(keyB[0], mixB[0], S, km0);
            }
        }
    } else {
        // 128-element ascending bitonic sort, 2 slots/lane (element j = s3*64+lane)
#pragma unroll
        for (int kk2 = 1; kk2 <= 6; kk2++) {
            const int K = 1 << kk2;
#pragma unroll
            for (int ss = kk2 - 1; ss >= 0; ss--) {
                const int S = 1 << ss;
                bool ascL = (lane & K) == 0;
                bool asc0 = (K == 64) ? true  : ascL;   // j&64 = 0 for slot0
                bool asc1 = (K == 64) ? false : ascL;   // j&64 = 64 for slot1
                bool km0 = ((lane & S) == 0) == asc0;
                bool km1 = ((lane & S) == 0) == asc1;
                cex(keyA[0], mixA[0], S, km0);
                cex(keyA[1], mixA[1], S, km1);
                cex(keyB[0], mixB[0], S, km0);
                cex(keyB[1], mixB[1], S, km1);
            }
        }
        // K=128 level. s=64: local exchange between slots (ascending: e0=min)
        {
            bool lA = (keyA[0] < keyA[1]) || (keyA[0] == keyA[1] && mixA[0] < mixA[1]);
            unsigned long long tk = keyA[0]; int ti = mixA[0];
            keyA[0] = lA ? keyA[0] : keyA[1];  mixA[0] = lA ? mixA[0] : mixA[1];
            keyA[1] = lA ? keyA[1] : tk;       mixA[1] = lA ? mixA[1] : ti;
            bool lB = (keyB[0] < keyB[1]) || (keyB[0] == keyB[1] && mixB[0] < mixB[1]);
            tk = keyB[0]; ti = mixB[0];
            keyB[0] = lB ? keyB[0] : keyB[1];  mixB[0] = lB ? mixB[0] : mixB[1];
            keyB[1] = lB ? keyB[1] : tk;       mixB[1] = lB ? mixB[1] : ti;
        }
        // s = 32..1, ascending everywhere (j&128 == 0)
#pragma unroll
        for (int ss = 5; ss >= 0; ss--) {
            const int S = 1 << ss;
            bool km = ((lane & S) == 0);
            cex(keyA[0], mixA[0], S, km);
            cex(keyA[1], mixA[1], S, km);
            cex(keyB[0], mixB[0], S, km);
            cex(keyB[1], mixB[1], S, km);
        }
    }
    // ranks 0..63 now live in slot0 by lane; emit the 40 smallest (key,idx).
    // Emission writes ALL 40 slots unconditionally -> sel needs no init.
    if (lane < KNN) {
        selb[rowA * KNN + lane] = mixA[0];
        selb[rowB * KNN + lane] = mixB[0];
    }

    // --- fused gather-reduce over the selected 40, BOTH rows ---
    {
        int o = lane & 31, h = lane >> 5;
        float s1A = 0.f, s2A = 0.f, s1B = 0.f, s2B = 0.f;
        float mxA = -__builtin_inff(), mnA = __builtin_inff();
        float mxB = -__builtin_inff(), mnB = __builtin_inff();
        const float* pb = p + bNP * 32 + o;
        for (int k = h * 20; k < h * 20 + 20; k++) {
            int mA = selb[rowA * KNN + k] & (NP - 1);   // defensive mask
            int mB = selb[rowB * KNN + k] & (NP - 1);
            float pvA = pb[(long)mA * 32];
            float pvB = pb[(long)mB * 32];
            s1A += pvA;
            s2A = fmaf(pvA, pvA, s2A);
            mxA = fmaxf(mxA, pvA);
            mnA = fminf(mnA, pvA);
            s1B += pvB;
            s2B = fmaf(pvB, pvB, s2B);
            mxB = fmaxf(mxB, pvB);
            mnB = fminf(mnB, pvB);
        }
        s1A += __shfl_xor(s1A, 32);
        s2A += __shfl_xor(s2A, 32);
        mxA = fmaxf(mxA, __shfl_xor(mxA, 32));
        mnA = fminf(mnA, __shfl_xor(mnA, 32));
        s1B += __shfl_xor(s1B, 32);
        s2B += __shfl_xor(s2B, 32);
        mxB = fmaxf(mxB, __shfl_xor(mxB, 32));
        mnB = fminf(mnB, __shfl_xor(mnB, 32));
        if (h == 0) {
            long bseA = (bNP + nA) * 32 + o;
            float qA = r[bseA];
            mmax[bseA] = mxA + qA;
            mmin[bseA] = mnA + qA;
            atomicAdd(&S1loc[o], s1A + 40.f * qA);
            atomicAdd(&S2loc[o], fmaf(2.f * qA, s1A, fmaf(40.f * qA, qA, s2A)));
            long bseB = (bNP + nB) * 32 + o;
            float qB = r[bseB];
            mmax[bseB] = mxB + qB;
            mmin[bseB] = mnB + qB;
            atomicAdd(&S1loc[o], s1B + 40.f * qB);
            atomicAdd(&S2loc[o], fmaf(2.f * qB, s1B, fmaf(40.f * qB, qB, s2B)));
        }
    }
    __syncthreads();
    if (tid < 32) {
        atomicAdd(&sums[tid], S1loc[tid]);
        atomicAdd(&sums[32 + tid], S2loc[tid]);
    }
}

// ---------------------------------------------------------------------------
// finish: per-channel BN affine from global sums, monotone max/min trick,
// LeakyReLU, residual, write slice of cat into d_out [B][128][N]
// ---------------------------------------------------------------------------
__global__ void finish_kernel(const float* __restrict__ mmax, const float* __restrict__ mmin,
                              const float* __restrict__ sums,
                              const float* __restrict__ g, const float* __restrict__ be,
                              const float* __restrict__ resid,
                              float* __restrict__ outb) {
    int id = blockIdx.x * 256 + threadIdx.x;     // B*32*N = 524288
    int b = id >> 16;
    int o = (id >> 11) & 31;
    int n = id & 2047;
    const float cntf = 655360.0f;                 // B*N*K
    float mean = sums[o] / cntf;
    float var = sums[32 + o] / cntf - mean * mean;
    float sc = g[o] / sqrtf(var + 1e-5f);
    float sh = be[o] - mean * sc;
    long bse = ((long)b * NP + n) * 32 + o;
    float v = (sc >= 0.f) ? mmax[bse] : mmin[bse];
    float y = sc * v + sh;
    y = (y >= 0.f) ? y : 0.2f * y;
    long ob = ((long)b * 128 + o) * NP + n;
    if (resid) y += resid[ob];
    outb[ob] = y;
}

// ---------------------------------------------------------------------------
// final in-place GEMM on d_out: out[b,o,n] = sum_c W5[o,c]*cat[b,c,n]
// ---------------------------------------------------------------------------
__global__ void final_gemm(const float* __restrict__ W5, float* __restrict__ out) {
    __shared__ __align__(16) float catL[128][32];
    int b = blockIdx.x >> 6;
    int n0 = (blockIdx.x & 63) * 32;
    int tid = threadIdx.x;
    for (int i = tid; i < 128 * 32; i += 256) {
        int c = i >> 5, nn = i & 31;
        catL[c][nn] = out[((long)b * 128 + c) * NP + n0 + nn];
    }
    __syncthreads();
    int og = tid >> 3, ng = tid & 7;
    int o0 = og * 4, nl = ng * 4;
    float acc[4][4] = {};
    for (int c = 0; c < 128; c++) {
        float4 cv = *(const float4*)&catL[c][nl];
#pragma unroll
        for (int i = 0; i < 4; i++) {
            float w = W5[(o0 + i) * 128 + c];
            acc[i][0] = fmaf(w, cv.x, acc[i][0]);
            acc[i][1] = fmaf(w, cv.y, acc[i][1]);
            acc[i][2] = fmaf(w, cv.z, acc[i][2]);
            acc[i][3] = fmaf(w, cv.w, acc[i][3]);
        }
    }
#pragma unroll
    for (int i = 0; i < 4; i++) {
        float4 vv = make_float4(acc[i][0], acc[i][1], acc[i][2], acc[i][3]);
        *(float4*)&out[((long)b * 128 + o0 + i) * NP + n0 + nl] = vv;
    }
}

extern "C" void kernel_launch(void* const* d_in, const int* in_sizes, int n_in,
                              void* d_out, int out_size, void* d_ws, size_t ws_size,
                              hipStream_t stream) {
    const float* x  = (const float*)d_in[0];
    const float* W1 = (const float*)d_in[1];
    const float* W2 = (const float*)d_in[2];
    const float* W3 = (const float*)d_in[3];
    const float* W4 = (const float*)d_in[4];
    const float* W5 = (const float*)d_in[5];
    const float* g1 = (const float*)d_in[6];
    const float* b1 = (const float*)d_in[7];
    const float* g2 = (const float*)d_in[8];
    const float* b2 = (const float*)d_in[9];
    const float* g3 = (const float*)d_in[10];
    const float* b3 = (const float*)d_in[11];
    const float* g4 = (const float*)d_in[12];
    const float* b4 = (const float*)d_in[13];
    float* out = (float*)d_out;
    float* ws  = (float*)d_ws;
    // ws layout (floats): p | r | mmax | mmin | xx | sums | XT
    float* p    = ws;
    float* r    = ws + 524288;
    float* mmax = ws + 1048576;
    float* mmin = ws + 1572864;
    float* xx   = ws + 2097152;
    float* sums = ws + 2113536;
    float* XT   = ws + 2113792;   // up to 8*2048*36 = 589824 floats
    hipMemsetAsync(sums, 0, 256 * sizeof(float), stream);

    // block 1 (C=9, CP=12, CPX=16)
    prep_kernel<9, 12, 16><<<2048, 256, 0, stream>>>(x, 9L * NP, W1, p, r, xx, XT);
    knn_kernel<9, 12, 16><<<1024, 512, 0, stream>>>(x, 9L * NP, p, r, xx, XT, mmax, mmin, sums);
    finish_kernel<<<2048, 256, 0, stream>>>(mmax, mmin, sums, g1, b1, nullptr, out);
    // block 2 (C=32, CP=32, CPX=36)
    const float* x1 = out;
    prep_kernel<32, 32, 36><<<2048, 256, 0, stream>>>(x1, 128L * NP, W2, p, r, xx, XT);
    knn_kernel<32, 32, 36><<<1024, 512, 0, stream>>>(x1, 128L * NP, p, r, xx, XT, mmax, mmin, sums + 64);
    finish_kernel<<<2048, 256, 0, stream>>>(mmax, mmin, sums + 64, g2, b2, x1, out + 32 * NP);
    // block 3
    const float* x2 = out + 32 * NP;
    prep_kernel<32, 32, 36><<<2048, 256, 0, stream>>>(x2, 128L * NP, W3, p, r, xx, XT);
    knn_kernel<32, 32, 36><<<1024, 512, 0, stream>>>(x2, 128L * NP, p, r, xx, XT, mmax, mmin, sums + 128);
    finish_kernel<<<2048, 256, 0, stream>>>(mmax, mmin, sums + 128, g3, b3, x2, out + 64 * NP);
    // block 4
    const float* x3 = out + 64 * NP;
    prep_kernel<32, 32, 36><<<2048, 256, 0, stream>>>(x3, 128L * NP, W4, p, r, xx, XT);
    knn_kernel<32, 32, 36><<<1024, 512, 0, stream>>>(x3, 128L * NP, p, r, xx, XT, mmax, mmin, sums + 192);
    finish_kernel<<<2048, 256, 0, stream>>>(mmax, mmin, sums + 192, g4, b4, x3, out + 96 * NP);

    final_gemm<<<512, 256, 0, stream>>>(W5, out);
}